// Round 10
// baseline (184.524 us; speedup 1.0000x reference)
//
#include <hip/hip_runtime.h>
#include <math.h>

#define NN 100000
#define NE 1600000
#define D 64
#define INDIM 18
#define CHUNKS 1024           // edge chunks for count/bin
#define BN 64                 // nodes per bucket (sort)
#define NBKT 1563             // ceil(NN / BN)
#define CAP 1536              // LDS edge capacity per bucket
#define NFRAG 72              // 48 update frags + 8 p_w1 + 16 p_w2

typedef __attribute__((ext_vector_type(8))) short s8b;    // 8 bf16 (4 VGPR)
typedef __attribute__((ext_vector_type(4))) float f32x4;  // MFMA acc

__device__ __forceinline__ float gelu_exact(float x) {
    return 0.5f * x * (1.0f + erff(x * 0.70710678118654752f));
}

// split f32 into bf16 hi + bf16 lo (round-to-nearest-even)
__device__ __forceinline__ void split_bf16(float f, unsigned short& h, unsigned short& l) {
    unsigned int u = __float_as_uint(f);
    unsigned int hb = (u + 0x7FFFu + ((u >> 16) & 1u)) >> 16;
    float hf = __uint_as_float(hb << 16);
    float lo = f - hf;
    unsigned int u2 = __float_as_uint(lo);
    unsigned int lb = (u2 + 0x7FFFu + ((u2 >> 16) & 1u)) >> 16;
    h = (unsigned short)hb; l = (unsigned short)lb;
}

// ---- pack B-fragments (hi/lo bf16, lane-major) ------------------------
__global__ __launch_bounds__(256) void pack_frags_kernel(
    const float* __restrict__ ww1, const float* __restrict__ ww2,
    const float* __restrict__ dw1, const float* __restrict__ pw1,
    const float* __restrict__ pw2, unsigned short* __restrict__ fragw)
{
    int tid = blockIdx.x * 256 + threadIdx.x;
    if (tid >= NFRAG * 64) return;
    int f = tid >> 6, l = tid & 63;
    unsigned short o[8];
    if (f < 48) {
        int x = f & 1, t = (f >> 1) & 3, s = (f >> 3) & 1, layer = f >> 4;
        const float* W = (layer == 0) ? ww1 : ((layer == 1) ? ww2 : dw1);
        #pragma unroll
        for (int j = 0; j < 8; ++j) {
            int k = s * 32 + (l >> 4) * 8 + j;
            int n = t * 16 + (l & 15);
            unsigned short hh, ll;
            split_bf16(W[k * D + n], hh, ll);
            o[j] = x ? ll : hh;
        }
    } else if (f < 56) {
        int g = f - 48, x = g & 1, t = (g >> 1) & 3;
        #pragma unroll
        for (int j = 0; j < 8; ++j) {
            int k = (l >> 4) * 8 + j;
            int n = t * 16 + (l & 15);
            float v = (k < INDIM) ? pw1[k * D + n] : 0.f;
            unsigned short hh, ll;
            split_bf16(v, hh, ll);
            o[j] = x ? ll : hh;
        }
    } else {
        int g = f - 56, x = g & 1, t = (g >> 1) & 3, s = (g >> 3) & 1;
        #pragma unroll
        for (int j = 0; j < 8; ++j) {
            int k = s * 32 + (l >> 4) * 8 + j;
            int n = t * 16 + (l & 15);
            unsigned short hh, ll;
            split_bf16(pw2[k * D + n], hh, ll);
            o[j] = x ? ll : hh;
        }
    }
    uint4 v;
    v.x = (unsigned)o[0] | ((unsigned)o[1] << 16);
    v.y = (unsigned)o[2] | ((unsigned)o[3] << 16);
    v.z = (unsigned)o[4] | ((unsigned)o[5] << 16);
    v.w = (unsigned)o[6] | ((unsigned)o[7] << 16);
    *(uint4*)&fragw[(size_t)f * 512 + l * 8] = v;
}

// -------- project via MFMA: h = (concat(x,grid) @ w1 ..gelu..) @ w2 + b2
__global__ __launch_bounds__(256) void project_mfma(
    const float* __restrict__ x, const float* __restrict__ grid,
    const unsigned short* __restrict__ fragw,
    const float* __restrict__ pb1, const float* __restrict__ pb2,
    float* __restrict__ h)
{
    __shared__ unsigned short midH[64 * 64];
    __shared__ unsigned short midL[64 * 64];
    const int tid = threadIdx.x;
    const int w = tid >> 6, l = tid & 63;
    const int q = l >> 4, c = l & 15;
    const int g0 = blockIdx.x * 64;
    const int rowbase = w * 16;

    union BU { uint4 u; s8b s; };

    const int arow = g0 + rowbase + c;
    const bool ok = arow < NN;
    float fv[8] = {0.f,0.f,0.f,0.f,0.f,0.f,0.f,0.f};
    if (q < 2) {
        if (ok) {
            const float* xp = x + (size_t)arow * 16 + q * 8;
            float4 f0 = *(const float4*)xp;
            float4 f1 = *(const float4*)(xp + 4);
            fv[0]=f0.x; fv[1]=f0.y; fv[2]=f0.z; fv[3]=f0.w;
            fv[4]=f1.x; fv[5]=f1.y; fv[6]=f1.z; fv[7]=f1.w;
        }
    } else if (q == 2) {
        if (ok) {
            float2 g2 = *(const float2*)(grid + (size_t)arow * 2);
            fv[0] = g2.x; fv[1] = g2.y;
        }
    }
    s8b aH[2], aL[2];
    #pragma unroll
    for (int j = 0; j < 8; ++j) {
        unsigned short hh, ll;
        split_bf16(fv[j], hh, ll);
        aH[0][j] = (short)hh; aL[0][j] = (short)ll;
    }

    f32x4 acc[4];
    #pragma unroll
    for (int t = 0; t < 4; ++t) acc[t] = (f32x4){0.f, 0.f, 0.f, 0.f};
    #pragma unroll
    for (int t = 0; t < 4; ++t) {
        BU bh, bl;
        int fb = 48 + t * 2;
        bh.u = *(const uint4*)&fragw[(size_t)fb * 512 + l * 8];
        bl.u = *(const uint4*)&fragw[(size_t)(fb + 1) * 512 + l * 8];
        acc[t] = __builtin_amdgcn_mfma_f32_16x16x32_bf16(aH[0], bh.s, acc[t], 0, 0, 0);
        acc[t] = __builtin_amdgcn_mfma_f32_16x16x32_bf16(aH[0], bl.s, acc[t], 0, 0, 0);
        acc[t] = __builtin_amdgcn_mfma_f32_16x16x32_bf16(aL[0], bh.s, acc[t], 0, 0, 0);
    }

    #pragma unroll
    for (int t = 0; t < 4; ++t) {
        float bias = pb1[t * 16 + c];
        #pragma unroll
        for (int r = 0; r < 4; ++r) {
            int grow = rowbase + q * 4 + r;
            float v = gelu_exact(acc[t][r] + bias);
            unsigned short hh, ll;
            split_bf16(v, hh, ll);
            int byte = ((grow * 128 + (t * 16 + c) * 2)) ^ ((grow & 7) << 4);
            midH[byte >> 1] = hh; midL[byte >> 1] = ll;
        }
    }
    __syncthreads();

    #pragma unroll
    for (int s = 0; s < 2; ++s) {
        int ar = rowbase + c;
        int abyte = (ar * 128 + s * 64 + q * 16) ^ ((ar & 7) << 4);
        aH[s] = *(const s8b*)((const char*)midH + abyte);
        aL[s] = *(const s8b*)((const char*)midL + abyte);
    }
    #pragma unroll
    for (int t = 0; t < 4; ++t) acc[t] = (f32x4){0.f, 0.f, 0.f, 0.f};
    #pragma unroll
    for (int s = 0; s < 2; ++s) {
        #pragma unroll
        for (int t = 0; t < 4; ++t) {
            BU bh, bl;
            int fb = 56 + s * 8 + t * 2;
            bh.u = *(const uint4*)&fragw[(size_t)fb * 512 + l * 8];
            bl.u = *(const uint4*)&fragw[(size_t)(fb + 1) * 512 + l * 8];
            acc[t] = __builtin_amdgcn_mfma_f32_16x16x32_bf16(aH[s], bh.s, acc[t], 0, 0, 0);
            acc[t] = __builtin_amdgcn_mfma_f32_16x16x32_bf16(aH[s], bl.s, acc[t], 0, 0, 0);
            acc[t] = __builtin_amdgcn_mfma_f32_16x16x32_bf16(aL[s], bh.s, acc[t], 0, 0, 0);
        }
    }
    #pragma unroll
    for (int t = 0; t < 4; ++t) {
        float bias = pb2[t * 16 + c];
        #pragma unroll
        for (int r = 0; r < 4; ++r) {
            int row = g0 + rowbase + q * 4 + r;
            if (row < NN) h[(size_t)row * D + t * 16 + c] = acc[t][r] + bias;
        }
    }
}

// ---------------- project VALU (ws fallback) ---------------------------
__global__ __launch_bounds__(256) void project_kernel(
    const float* __restrict__ x, const float* __restrict__ grid,
    const float* __restrict__ w1, const float* __restrict__ b1,
    const float* __restrict__ w2, const float* __restrict__ b2,
    float* __restrict__ h)
{
    int n = blockIdx.x * 256 + threadIdx.x;
    if (n >= NN) return;

    float in[INDIM];
    {
        const float4* xr = (const float4*)(x + (size_t)n * 16);
        float4 a = xr[0], b = xr[1], c = xr[2], d = xr[3];
        in[0]=a.x; in[1]=a.y; in[2]=a.z; in[3]=a.w;
        in[4]=b.x; in[5]=b.y; in[6]=b.z; in[7]=b.w;
        in[8]=c.x; in[9]=c.y; in[10]=c.z; in[11]=c.w;
        in[12]=d.x; in[13]=d.y; in[14]=d.z; in[15]=d.w;
        float2 g = *(const float2*)(grid + (size_t)n * 2);
        in[16]=g.x; in[17]=g.y;
    }

    float mid[D];
    for (int j1 = 0; j1 < D; j1 += 4) {
        float a0 = b1[j1], a1 = b1[j1+1], a2 = b1[j1+2], a3 = b1[j1+3];
        #pragma unroll
        for (int k = 0; k < INDIM; ++k) {
            float t = in[k];
            a0 += t * w1[k*D + j1];
            a1 += t * w1[k*D + j1+1];
            a2 += t * w1[k*D + j1+2];
            a3 += t * w1[k*D + j1+3];
        }
        mid[j1]   = gelu_exact(a0);
        mid[j1+1] = gelu_exact(a1);
        mid[j1+2] = gelu_exact(a2);
        mid[j1+3] = gelu_exact(a3);
    }

    float acc[D];
    #pragma unroll
    for (int j = 0; j < D; ++j) acc[j] = b2[j];
    for (int j1 = 0; j1 < D; j1 += 4) {
        float t0 = mid[j1], t1 = mid[j1+1], t2 = mid[j1+2], t3 = mid[j1+3];
        #pragma unroll
        for (int j = 0; j < D; ++j)
            acc[j] += t0 * w2[j1*D + j]     + t1 * w2[(j1+1)*D + j]
                    + t2 * w2[(j1+2)*D + j] + t3 * w2[(j1+3)*D + j];
    }

    float* hrow = h + (size_t)n * D;
    #pragma unroll
    for (int j = 0; j < D; j += 4) {
        float4 v = { acc[j], acc[j+1], acc[j+2], acc[j+3] };
        *(float4*)(hrow + j) = v;
    }
}

// ---- sort step 1: per-chunk LDS histogram -> counts[chunk][bucket] ----
__global__ __launch_bounds__(256) void count_kernel(
    const int* __restrict__ ei, unsigned short* __restrict__ counts)
{
    __shared__ int s_hist[NBKT];
    const int blk = blockIdx.x, tid = threadIdx.x;
    const int* __restrict__ dst = ei + NE;
    for (int i = tid; i < NBKT; i += 256) s_hist[i] = 0;
    __syncthreads();
    for (int e = blk * 256 + tid; e < NE; e += CHUNKS * 256)
        atomicAdd(&s_hist[dst[e] / BN], 1);
    __syncthreads();
    for (int b = tid; b < NBKT; b += 256)
        counts[(size_t)blk * NBKT + b] = (unsigned short)s_hist[b];
}

// ---- sort step 2: per-bucket column scan over 1024 chunks (in place) --
// thread tid handles chunks [tid*4, tid*4+4); serial prefix + block scan.
__global__ __launch_bounds__(256) void scan_cols_kernel(
    unsigned short* __restrict__ counts, int* __restrict__ btotal)
{
    __shared__ int s[256];
    const int g = blockIdx.x, tid = threadIdx.x;
    int c[4];
    #pragma unroll
    for (int i = 0; i < 4; ++i)
        c[i] = counts[(size_t)(tid * 4 + i) * NBKT + g];
    int sum = c[0] + c[1] + c[2] + c[3];
    s[tid] = sum; __syncthreads();
    for (int off = 1; off < 256; off <<= 1) {
        int val = s[tid];
        int add = (tid >= off) ? s[tid - off] : 0;
        __syncthreads();
        s[tid] = val + add;
        __syncthreads();
    }
    int base = s[tid] - sum;            // exclusive across threads
    #pragma unroll
    for (int i = 0; i < 4; ++i) {
        counts[(size_t)(tid * 4 + i) * NBKT + g] = (unsigned short)base;
        base += c[i];
    }
    if (tid == 255) btotal[g] = s[255];
}

// ---- sort step 3: scan bucket totals -> offs[0..NBKT] ----------------
__global__ __launch_bounds__(1024) void scan_bsum_kernel(
    const int* __restrict__ btotal, int* __restrict__ offs)
{
    __shared__ int s[1024];
    const int tid = threadIdx.x;
    int b0 = 2 * tid, b1 = 2 * tid + 1;
    int v0 = (b0 < NBKT) ? btotal[b0] : 0;
    int v1 = (b1 < NBKT) ? btotal[b1] : 0;
    int sum = v0 + v1;
    s[tid] = sum; __syncthreads();
    for (int off = 1; off < 1024; off <<= 1) {
        int val = s[tid];
        int add = (tid >= off) ? s[tid - off] : 0;
        __syncthreads();
        s[tid] = val + add;
        __syncthreads();
    }
    int base = s[tid] - sum;
    if (b0 < NBKT) offs[b0] = base;
    if (b1 < NBKT) offs[b1] = base + v0;
    if (tid == 0)  offs[NBKT] = NE;
}

// ---- sort step 4: scatter packed (src<<6 | dst%64), LDS cursors ------
__global__ __launch_bounds__(256) void bin_kernel(
    const int* __restrict__ ei, const unsigned short* __restrict__ counts,
    const int* __restrict__ offs, int* __restrict__ packed)
{
    __shared__ int s_cur[NBKT];
    const int blk = blockIdx.x, tid = threadIdx.x;
    const int* __restrict__ dst = ei + NE;
    for (int b = tid; b < NBKT; b += 256)
        s_cur[b] = offs[b] + (int)counts[(size_t)blk * NBKT + b];
    __syncthreads();
    for (int e = blk * 256 + tid; e < NE; e += CHUNKS * 256) {
        int d = dst[e];
        int s = ei[e];
        int pos = atomicAdd(&s_cur[d / BN], 1);
        packed[pos] = (s << 6) | (d & (BN - 1));
    }
}

// ---- FUSED: per-bucket sort + gather-aggregate (LDS) + MFMA update ----
__global__ __launch_bounds__(256) void sortagg_update_kernel(
    const int* __restrict__ offs, const int* __restrict__ packed,
    const float* __restrict__ h, const unsigned short* __restrict__ fragw,
    const float* __restrict__ wb1, const float* __restrict__ wb2,
    const float* __restrict__ db1, const float* __restrict__ dw2,
    const float* __restrict__ db2, float* __restrict__ out)
{
    __shared__ int s_off[BN + 1];
    __shared__ int s_cur[BN];
    __shared__ int s_src[CAP];
    __shared__ float s_aggr[BN][65];          // padded: conflict-spread
    __shared__ unsigned short midH[64 * 64];
    __shared__ unsigned short midL[64 * 64];
    const int b = blockIdx.x, tid = threadIdx.x;
    const int start = offs[b], end = offs[b + 1];
    const int cnt = end - start;
    const int wid = tid >> 6, lane = tid & 63;
    const int base = b * BN;

    // ================= phase 1: sort + gather-aggregate ================
    if (cnt <= CAP) {
        if (tid < BN) s_cur[tid] = 0;
        __syncthreads();
        for (int e = start + tid; e < end; e += 256)
            atomicAdd(&s_cur[packed[e] & (BN - 1)], 1);
        __syncthreads();
        if (tid < 64) {
            int v = s_cur[tid];
            int incl = v;
            #pragma unroll
            for (int off = 1; off < 64; off <<= 1) {
                int u = __shfl_up(incl, off, 64);
                if (tid >= off) incl += u;
            }
            s_off[tid] = incl - v;
            if (tid == 63) s_off[64] = cnt;
        }
        __syncthreads();
        if (tid < BN) s_cur[tid] = s_off[tid];
        __syncthreads();
        for (int e = start + tid; e < end; e += 256) {
            int p = packed[e];
            int pos = atomicAdd(&s_cur[p & (BN - 1)], 1);
            s_src[pos] = p >> 6;
        }
        __syncthreads();
        for (int m = wid; m < BN; m += 4) {
            int s0 = s_off[m], s1 = s_off[m + 1];
            float a0=0,a1=0,a2=0,a3=0,a4=0,a5=0,a6=0,a7=0;
            int e = s0;
            for (; e + 8 <= s1; e += 8) {
                int i0=s_src[e],  i1=s_src[e+1],i2=s_src[e+2],i3=s_src[e+3];
                int i4=s_src[e+4],i5=s_src[e+5],i6=s_src[e+6],i7=s_src[e+7];
                a0 += h[(size_t)i0*D+lane]; a1 += h[(size_t)i1*D+lane];
                a2 += h[(size_t)i2*D+lane]; a3 += h[(size_t)i3*D+lane];
                a4 += h[(size_t)i4*D+lane]; a5 += h[(size_t)i5*D+lane];
                a6 += h[(size_t)i6*D+lane]; a7 += h[(size_t)i7*D+lane];
            }
            for (; e < s1; ++e) a0 += h[(size_t)s_src[e]*D+lane];
            s_aggr[m][lane] = ((a0+a1)+(a2+a3))+((a4+a5)+(a6+a7));
        }
    } else {
        // slow fallback (LDS overflow; not expected for this input)
        for (int m = wid; m < BN; m += 4) {
            float a = 0.f;
            for (int e = start; e < end; ++e) {
                int p = packed[e];
                if ((p & (BN - 1)) == m) a += h[(size_t)(p >> 6) * D + lane];
            }
            s_aggr[m][lane] = a;
        }
    }
    __syncthreads();

    // ================= phase 2: MFMA update + decode ===================
    const int w = wid, l = lane;
    const int q = l >> 4, c = l & 15;
    const int g0 = base;
    const int rowbase = w * 16;

    union BU { uint4 u; s8b s; };

    s8b aH[2], aL[2];
    #pragma unroll
    for (int s = 0; s < 2; ++s) {
        const float* hp = h + (size_t)(g0 + rowbase + c) * D + s * 32 + q * 8;
        float4 f0 = *(const float4*)hp;
        float4 f1 = *(const float4*)(hp + 4);
        float fv[8] = {f0.x, f0.y, f0.z, f0.w, f1.x, f1.y, f1.z, f1.w};
        #pragma unroll
        for (int j = 0; j < 8; ++j) {
            unsigned short hh, ll;
            split_bf16(fv[j], hh, ll);
            aH[s][j] = (short)hh; aL[s][j] = (short)ll;
        }
    }

    f32x4 acc[4];
    #pragma unroll
    for (int t = 0; t < 4; ++t) acc[t] = (f32x4){0.f, 0.f, 0.f, 0.f};
    #pragma unroll
    for (int s = 0; s < 2; ++s) {
        #pragma unroll
        for (int t = 0; t < 4; ++t) {
            BU bh, bl;
            int fb = ((0 * 2 + s) * 4 + t) * 2;
            bh.u = *(const uint4*)&fragw[(size_t)fb * 512 + l * 8];
            bl.u = *(const uint4*)&fragw[(size_t)(fb + 1) * 512 + l * 8];
            acc[t] = __builtin_amdgcn_mfma_f32_16x16x32_bf16(aH[s], bh.s, acc[t], 0, 0, 0);
            acc[t] = __builtin_amdgcn_mfma_f32_16x16x32_bf16(aH[s], bl.s, acc[t], 0, 0, 0);
            acc[t] = __builtin_amdgcn_mfma_f32_16x16x32_bf16(aL[s], bh.s, acc[t], 0, 0, 0);
        }
    }

    #pragma unroll
    for (int t = 0; t < 4; ++t) {
        float bias = wb1[t * 16 + c];
        #pragma unroll
        for (int r = 0; r < 4; ++r) {
            int grow = rowbase + q * 4 + r;
            float v = gelu_exact(acc[t][r] + bias);
            unsigned short hh, ll;
            split_bf16(v, hh, ll);
            int byte = ((grow * 128 + (t * 16 + c) * 2)) ^ ((grow & 7) << 4);
            midH[byte >> 1] = hh; midL[byte >> 1] = ll;
        }
    }
    __syncthreads();

    #pragma unroll
    for (int s = 0; s < 2; ++s) {
        int ar = rowbase + c;
        int abyte = (ar * 128 + s * 64 + q * 16) ^ ((ar & 7) << 4);
        aH[s] = *(const s8b*)((const char*)midH + abyte);
        aL[s] = *(const s8b*)((const char*)midL + abyte);
    }
    #pragma unroll
    for (int t = 0; t < 4; ++t) acc[t] = (f32x4){0.f, 0.f, 0.f, 0.f};
    #pragma unroll
    for (int s = 0; s < 2; ++s) {
        #pragma unroll
        for (int t = 0; t < 4; ++t) {
            BU bh, bl;
            int fb = ((1 * 2 + s) * 4 + t) * 2;
            bh.u = *(const uint4*)&fragw[(size_t)fb * 512 + l * 8];
            bl.u = *(const uint4*)&fragw[(size_t)(fb + 1) * 512 + l * 8];
            acc[t] = __builtin_amdgcn_mfma_f32_16x16x32_bf16(aH[s], bh.s, acc[t], 0, 0, 0);
            acc[t] = __builtin_amdgcn_mfma_f32_16x16x32_bf16(aH[s], bl.s, acc[t], 0, 0, 0);
            acc[t] = __builtin_amdgcn_mfma_f32_16x16x32_bf16(aL[s], bh.s, acc[t], 0, 0, 0);
        }
    }
    __syncthreads();

    #pragma unroll
    for (int t = 0; t < 4; ++t) {
        float bias = wb2[t * 16 + c];
        #pragma unroll
        for (int r = 0; r < 4; ++r) {
            int grow = rowbase + q * 4 + r;
            float ag = s_aggr[grow][t * 16 + c];
            float v = gelu_exact(acc[t][r] + bias + ag);
            unsigned short hh, ll;
            split_bf16(v, hh, ll);
            int byte = ((grow * 128 + (t * 16 + c) * 2)) ^ ((grow & 7) << 4);
            midH[byte >> 1] = hh; midL[byte >> 1] = ll;
        }
    }
    __syncthreads();

    #pragma unroll
    for (int s = 0; s < 2; ++s) {
        int ar = rowbase + c;
        int abyte = (ar * 128 + s * 64 + q * 16) ^ ((ar & 7) << 4);
        aH[s] = *(const s8b*)((const char*)midH + abyte);
        aL[s] = *(const s8b*)((const char*)midL + abyte);
    }
    #pragma unroll
    for (int t = 0; t < 4; ++t) acc[t] = (f32x4){0.f, 0.f, 0.f, 0.f};
    #pragma unroll
    for (int s = 0; s < 2; ++s) {
        #pragma unroll
        for (int t = 0; t < 4; ++t) {
            BU bh, bl;
            int fb = ((2 * 2 + s) * 4 + t) * 2;
            bh.u = *(const uint4*)&fragw[(size_t)fb * 512 + l * 8];
            bl.u = *(const uint4*)&fragw[(size_t)(fb + 1) * 512 + l * 8];
            acc[t] = __builtin_amdgcn_mfma_f32_16x16x32_bf16(aH[s], bh.s, acc[t], 0, 0, 0);
            acc[t] = __builtin_amdgcn_mfma_f32_16x16x32_bf16(aH[s], bl.s, acc[t], 0, 0, 0);
            acc[t] = __builtin_amdgcn_mfma_f32_16x16x32_bf16(aL[s], bh.s, acc[t], 0, 0, 0);
        }
    }

    float p[4] = {0.f, 0.f, 0.f, 0.f};
    #pragma unroll
    for (int t = 0; t < 4; ++t) {
        float bias = db1[t * 16 + c];
        float wv = dw2[t * 16 + c];
        #pragma unroll
        for (int r = 0; r < 4; ++r)
            p[r] += gelu_exact(acc[t][r] + bias) * wv;
    }
    #pragma unroll
    for (int m = 1; m < 16; m <<= 1) {
        #pragma unroll
        for (int r = 0; r < 4; ++r) p[r] += __shfl_xor(p[r], m, 16);
    }
    if (c == 0) {
        float b2v = db2[0];
        #pragma unroll
        for (int r = 0; r < 4; ++r) {
            int row = g0 + rowbase + q * 4 + r;
            if (row < NN) out[row] = p[r] + b2v;
        }
    }
}

// ---------------- legacy atomic aggregate (ws fallback) ----------------
__global__ __launch_bounds__(256) void aggregate_kernel(
    const int* __restrict__ ei, const float* __restrict__ h,
    float* __restrict__ aggr)
{
    int t = blockIdx.x * 256 + threadIdx.x;
    int e = t >> 6;
    int lane = t & 63;
    if (e >= NE) return;
    int src = ei[e];
    int dst = ei[NE + e];
    float v = h[(size_t)src * D + lane];
    atomicAdd(&aggr[(size_t)dst * D + lane], v);
}

// ------- legacy VALU update (ws fallback) ------------------------------
__global__ __launch_bounds__(256) void update_decode_valu(
    const float* __restrict__ h, const float* __restrict__ aggr,
    const float* __restrict__ ww1, const float* __restrict__ wb1,
    const float* __restrict__ ww2, const float* __restrict__ wb2,
    const float* __restrict__ dw1, const float* __restrict__ db1,
    const float* __restrict__ dw2, const float* __restrict__ db2,
    float* __restrict__ out)
{
    int n = blockIdx.x * 256 + threadIdx.x;
    if (n >= NN) return;
    float hrow[D];
    #pragma unroll
    for (int j = 0; j < D; j += 4) {
        float4 v = *(const float4*)(h + (size_t)n * D + j);
        hrow[j] = v.x; hrow[j+1] = v.y; hrow[j+2] = v.z; hrow[j+3] = v.w;
    }
    float mid[D];
    for (int j1 = 0; j1 < D; j1 += 4) {
        float a0 = wb1[j1], a1 = wb1[j1+1], a2 = wb1[j1+2], a3 = wb1[j1+3];
        #pragma unroll
        for (int k = 0; k < D; ++k) {
            float t = hrow[k];
            a0 += t * ww1[k*D + j1];   a1 += t * ww1[k*D + j1+1];
            a2 += t * ww1[k*D + j1+2]; a3 += t * ww1[k*D + j1+3];
        }
        mid[j1]=gelu_exact(a0); mid[j1+1]=gelu_exact(a1);
        mid[j1+2]=gelu_exact(a2); mid[j1+3]=gelu_exact(a3);
    }
    #pragma unroll
    for (int j = 0; j < D; j += 4) {
        float4 v = *(const float4*)(aggr + (size_t)n * D + j);
        hrow[j]=wb2[j]+v.x; hrow[j+1]=wb2[j+1]+v.y;
        hrow[j+2]=wb2[j+2]+v.z; hrow[j+3]=wb2[j+3]+v.w;
    }
    for (int j1 = 0; j1 < D; j1 += 4) {
        float t0=mid[j1], t1=mid[j1+1], t2=mid[j1+2], t3=mid[j1+3];
        #pragma unroll
        for (int j = 0; j < D; ++j)
            hrow[j] += t0*ww2[j1*D+j] + t1*ww2[(j1+1)*D+j]
                     + t2*ww2[(j1+2)*D+j] + t3*ww2[(j1+3)*D+j];
    }
    #pragma unroll
    for (int j = 0; j < D; ++j) hrow[j] = gelu_exact(hrow[j]);
    float o = db2[0];
    for (int j1 = 0; j1 < D; j1 += 4) {
        float a0 = db1[j1], a1 = db1[j1+1], a2 = db1[j1+2], a3 = db1[j1+3];
        #pragma unroll
        for (int k = 0; k < D; ++k) {
            float t = hrow[k];
            a0 += t*dw1[k*D+j1];   a1 += t*dw1[k*D+j1+1];
            a2 += t*dw1[k*D+j1+2]; a3 += t*dw1[k*D+j1+3];
        }
        o += gelu_exact(a0)*dw2[j1] + gelu_exact(a1)*dw2[j1+1]
           + gelu_exact(a2)*dw2[j1+2] + gelu_exact(a3)*dw2[j1+3];
    }
    out[n] = o;
}

extern "C" void kernel_launch(void* const* d_in, const int* in_sizes, int n_in,
                              void* d_out, int out_size, void* d_ws, size_t ws_size,
                              hipStream_t stream) {
    const float* x    = (const float*)d_in[0];
    const float* grid = (const float*)d_in[1];
    const int*   ei   = (const int*)d_in[2];
    const float* p_w1 = (const float*)d_in[4];
    const float* p_b1 = (const float*)d_in[5];
    const float* p_w2 = (const float*)d_in[6];
    const float* p_b2 = (const float*)d_in[7];
    const float* w_w1 = (const float*)d_in[8];
    const float* w_b1 = (const float*)d_in[9];
    const float* w_w2 = (const float*)d_in[10];
    const float* w_b2 = (const float*)d_in[11];
    const float* d_w1 = (const float*)d_in[12];
    const float* d_b1 = (const float*)d_in[13];
    const float* d_w2 = (const float*)d_in[14];
    const float* d_b2 = (const float*)d_in[15];
    float* out = (float*)d_out;

    float* h    = (float*)d_ws;                            // [NN, D] f32
    float* aggr = h + (size_t)NN * D;                      // [NN, D] f32 (fallback only)
    unsigned short* counts = (unsigned short*)(aggr + (size_t)NN * D); // [CHUNKS][NBKT] u16
    int* btotal = (int*)(counts + (size_t)CHUNKS * NBKT);  // [NBKT]
    int* offs   = btotal + NBKT;                           // [NBKT+1]
    int* packed = offs + NBKT + 1;                         // [NE]
    unsigned short* fragw =
        (unsigned short*)((((uintptr_t)(packed + NE)) + 15) & ~(uintptr_t)15); // [NFRAG*512] u16

    size_t need = ((char*)(fragw + NFRAG * 512)) - (char*)d_ws;

    if (ws_size >= need) {
        pack_frags_kernel<<<(NFRAG * 64 + 255) / 256, 256, 0, stream>>>(
            w_w1, w_w2, d_w1, p_w1, p_w2, fragw);
        project_mfma<<<(NN + 63) / 64, 256, 0, stream>>>(
            x, grid, fragw, p_b1, p_b2, h);
        count_kernel    <<<CHUNKS, 256, 0, stream>>>(ei, counts);
        scan_cols_kernel<<<NBKT,   256, 0, stream>>>(counts, btotal);
        scan_bsum_kernel<<<1,     1024, 0, stream>>>(btotal, offs);
        bin_kernel      <<<CHUNKS, 256, 0, stream>>>(ei, counts, offs, packed);
        sortagg_update_kernel<<<NBKT, 256, 0, stream>>>(
            offs, packed, h, fragw, w_b1, w_b2, d_b1, d_w2, d_b2, out);
    } else {
        project_kernel<<<(NN + 255) / 256, 256, 0, stream>>>(
            x, grid, p_w1, p_b1, p_w2, p_b2, h);
        hipMemsetAsync(aggr, 0, (size_t)NN * D * sizeof(float), stream);
        aggregate_kernel<<<(size_t)NE * 64 / 256, 256, 0, stream>>>(ei, h, aggr);
        update_decode_valu<<<(NN + 255) / 256, 256, 0, stream>>>(
            h, aggr, w_w1, w_b1, w_w2, w_b2, d_w1, d_b1, d_w2, d_b2, out);
    }
}

// Round 11
// 172.145 us; speedup vs baseline: 1.0719x; 1.0719x over previous
//
#include <hip/hip_runtime.h>
#include <math.h>

#define NN 100000
#define NE 1600000
#define D 64
#define INDIM 18
#define CHUNKS 1024           // edge chunks for count/bin
#define BN 64                 // nodes per bucket (sort)
#define NBKT 1563             // ceil(NN / BN)
#define CAP 1536              // LDS edge capacity per bucket
#define NFRAG 72              // 48 update frags + 8 p_w1 + 16 p_w2

typedef __attribute__((ext_vector_type(8))) short s8b;    // 8 bf16 (4 VGPR)
typedef __attribute__((ext_vector_type(4))) float f32x4;  // MFMA acc

__device__ __forceinline__ float gelu_exact(float x) {
    return 0.5f * x * (1.0f + erff(x * 0.70710678118654752f));
}

// split f32 into bf16 hi + bf16 lo (round-to-nearest-even)
__device__ __forceinline__ void split_bf16(float f, unsigned short& h, unsigned short& l) {
    unsigned int u = __float_as_uint(f);
    unsigned int hb = (u + 0x7FFFu + ((u >> 16) & 1u)) >> 16;
    float hf = __uint_as_float(hb << 16);
    float lo = f - hf;
    unsigned int u2 = __float_as_uint(lo);
    unsigned int lb = (u2 + 0x7FFFu + ((u2 >> 16) & 1u)) >> 16;
    h = (unsigned short)hb; l = (unsigned short)lb;
}

// ---- pack B-fragments (hi/lo bf16, lane-major) ------------------------
__global__ __launch_bounds__(256) void pack_frags_kernel(
    const float* __restrict__ ww1, const float* __restrict__ ww2,
    const float* __restrict__ dw1, const float* __restrict__ pw1,
    const float* __restrict__ pw2, unsigned short* __restrict__ fragw)
{
    int tid = blockIdx.x * 256 + threadIdx.x;
    if (tid >= NFRAG * 64) return;
    int f = tid >> 6, l = tid & 63;
    unsigned short o[8];
    if (f < 48) {
        int x = f & 1, t = (f >> 1) & 3, s = (f >> 3) & 1, layer = f >> 4;
        const float* W = (layer == 0) ? ww1 : ((layer == 1) ? ww2 : dw1);
        #pragma unroll
        for (int j = 0; j < 8; ++j) {
            int k = s * 32 + (l >> 4) * 8 + j;
            int n = t * 16 + (l & 15);
            unsigned short hh, ll;
            split_bf16(W[k * D + n], hh, ll);
            o[j] = x ? ll : hh;
        }
    } else if (f < 56) {
        int g = f - 48, x = g & 1, t = (g >> 1) & 3;
        #pragma unroll
        for (int j = 0; j < 8; ++j) {
            int k = (l >> 4) * 8 + j;
            int n = t * 16 + (l & 15);
            float v = (k < INDIM) ? pw1[k * D + n] : 0.f;
            unsigned short hh, ll;
            split_bf16(v, hh, ll);
            o[j] = x ? ll : hh;
        }
    } else {
        int g = f - 56, x = g & 1, t = (g >> 1) & 3, s = (g >> 3) & 1;
        #pragma unroll
        for (int j = 0; j < 8; ++j) {
            int k = s * 32 + (l >> 4) * 8 + j;
            int n = t * 16 + (l & 15);
            unsigned short hh, ll;
            split_bf16(pw2[k * D + n], hh, ll);
            o[j] = x ? ll : hh;
        }
    }
    uint4 v;
    v.x = (unsigned)o[0] | ((unsigned)o[1] << 16);
    v.y = (unsigned)o[2] | ((unsigned)o[3] << 16);
    v.z = (unsigned)o[4] | ((unsigned)o[5] << 16);
    v.w = (unsigned)o[6] | ((unsigned)o[7] << 16);
    *(uint4*)&fragw[(size_t)f * 512 + l * 8] = v;
}

// -------- project via MFMA: h = (concat(x,grid) @ w1 ..gelu..) @ w2 + b2
__global__ __launch_bounds__(256) void project_mfma(
    const float* __restrict__ x, const float* __restrict__ grid,
    const unsigned short* __restrict__ fragw,
    const float* __restrict__ pb1, const float* __restrict__ pb2,
    float* __restrict__ h)
{
    __shared__ unsigned short midH[64 * 64];
    __shared__ unsigned short midL[64 * 64];
    const int tid = threadIdx.x;
    const int w = tid >> 6, l = tid & 63;
    const int q = l >> 4, c = l & 15;
    const int g0 = blockIdx.x * 64;
    const int rowbase = w * 16;

    union BU { uint4 u; s8b s; };

    const int arow = g0 + rowbase + c;
    const bool ok = arow < NN;
    float fv[8] = {0.f,0.f,0.f,0.f,0.f,0.f,0.f,0.f};
    if (q < 2) {
        if (ok) {
            const float* xp = x + (size_t)arow * 16 + q * 8;
            float4 f0 = *(const float4*)xp;
            float4 f1 = *(const float4*)(xp + 4);
            fv[0]=f0.x; fv[1]=f0.y; fv[2]=f0.z; fv[3]=f0.w;
            fv[4]=f1.x; fv[5]=f1.y; fv[6]=f1.z; fv[7]=f1.w;
        }
    } else if (q == 2) {
        if (ok) {
            float2 g2 = *(const float2*)(grid + (size_t)arow * 2);
            fv[0] = g2.x; fv[1] = g2.y;
        }
    }
    s8b aH[2], aL[2];
    #pragma unroll
    for (int j = 0; j < 8; ++j) {
        unsigned short hh, ll;
        split_bf16(fv[j], hh, ll);
        aH[0][j] = (short)hh; aL[0][j] = (short)ll;
    }

    f32x4 acc[4];
    #pragma unroll
    for (int t = 0; t < 4; ++t) acc[t] = (f32x4){0.f, 0.f, 0.f, 0.f};
    #pragma unroll
    for (int t = 0; t < 4; ++t) {
        BU bh, bl;
        int fb = 48 + t * 2;
        bh.u = *(const uint4*)&fragw[(size_t)fb * 512 + l * 8];
        bl.u = *(const uint4*)&fragw[(size_t)(fb + 1) * 512 + l * 8];
        acc[t] = __builtin_amdgcn_mfma_f32_16x16x32_bf16(aH[0], bh.s, acc[t], 0, 0, 0);
        acc[t] = __builtin_amdgcn_mfma_f32_16x16x32_bf16(aH[0], bl.s, acc[t], 0, 0, 0);
        acc[t] = __builtin_amdgcn_mfma_f32_16x16x32_bf16(aL[0], bh.s, acc[t], 0, 0, 0);
    }

    #pragma unroll
    for (int t = 0; t < 4; ++t) {
        float bias = pb1[t * 16 + c];
        #pragma unroll
        for (int r = 0; r < 4; ++r) {
            int grow = rowbase + q * 4 + r;
            float v = gelu_exact(acc[t][r] + bias);
            unsigned short hh, ll;
            split_bf16(v, hh, ll);
            int byte = ((grow * 128 + (t * 16 + c) * 2)) ^ ((grow & 7) << 4);
            midH[byte >> 1] = hh; midL[byte >> 1] = ll;
        }
    }
    __syncthreads();

    #pragma unroll
    for (int s = 0; s < 2; ++s) {
        int ar = rowbase + c;
        int abyte = (ar * 128 + s * 64 + q * 16) ^ ((ar & 7) << 4);
        aH[s] = *(const s8b*)((const char*)midH + abyte);
        aL[s] = *(const s8b*)((const char*)midL + abyte);
    }
    #pragma unroll
    for (int t = 0; t < 4; ++t) acc[t] = (f32x4){0.f, 0.f, 0.f, 0.f};
    #pragma unroll
    for (int s = 0; s < 2; ++s) {
        #pragma unroll
        for (int t = 0; t < 4; ++t) {
            BU bh, bl;
            int fb = 56 + s * 8 + t * 2;
            bh.u = *(const uint4*)&fragw[(size_t)fb * 512 + l * 8];
            bl.u = *(const uint4*)&fragw[(size_t)(fb + 1) * 512 + l * 8];
            acc[t] = __builtin_amdgcn_mfma_f32_16x16x32_bf16(aH[s], bh.s, acc[t], 0, 0, 0);
            acc[t] = __builtin_amdgcn_mfma_f32_16x16x32_bf16(aH[s], bl.s, acc[t], 0, 0, 0);
            acc[t] = __builtin_amdgcn_mfma_f32_16x16x32_bf16(aL[s], bh.s, acc[t], 0, 0, 0);
        }
    }
    #pragma unroll
    for (int t = 0; t < 4; ++t) {
        float bias = pb2[t * 16 + c];
        #pragma unroll
        for (int r = 0; r < 4; ++r) {
            int row = g0 + rowbase + q * 4 + r;
            if (row < NN) h[(size_t)row * D + t * 16 + c] = acc[t][r] + bias;
        }
    }
}

// ---------------- project VALU (ws fallback) ---------------------------
__global__ __launch_bounds__(256) void project_kernel(
    const float* __restrict__ x, const float* __restrict__ grid,
    const float* __restrict__ w1, const float* __restrict__ b1,
    const float* __restrict__ w2, const float* __restrict__ b2,
    float* __restrict__ h)
{
    int n = blockIdx.x * 256 + threadIdx.x;
    if (n >= NN) return;

    float in[INDIM];
    {
        const float4* xr = (const float4*)(x + (size_t)n * 16);
        float4 a = xr[0], b = xr[1], c = xr[2], d = xr[3];
        in[0]=a.x; in[1]=a.y; in[2]=a.z; in[3]=a.w;
        in[4]=b.x; in[5]=b.y; in[6]=b.z; in[7]=b.w;
        in[8]=c.x; in[9]=c.y; in[10]=c.z; in[11]=c.w;
        in[12]=d.x; in[13]=d.y; in[14]=d.z; in[15]=d.w;
        float2 g = *(const float2*)(grid + (size_t)n * 2);
        in[16]=g.x; in[17]=g.y;
    }

    float mid[D];
    for (int j1 = 0; j1 < D; j1 += 4) {
        float a0 = b1[j1], a1 = b1[j1+1], a2 = b1[j1+2], a3 = b1[j1+3];
        #pragma unroll
        for (int k = 0; k < INDIM; ++k) {
            float t = in[k];
            a0 += t * w1[k*D + j1];
            a1 += t * w1[k*D + j1+1];
            a2 += t * w1[k*D + j1+2];
            a3 += t * w1[k*D + j1+3];
        }
        mid[j1]   = gelu_exact(a0);
        mid[j1+1] = gelu_exact(a1);
        mid[j1+2] = gelu_exact(a2);
        mid[j1+3] = gelu_exact(a3);
    }

    float acc[D];
    #pragma unroll
    for (int j = 0; j < D; ++j) acc[j] = b2[j];
    for (int j1 = 0; j1 < D; j1 += 4) {
        float t0 = mid[j1], t1 = mid[j1+1], t2 = mid[j1+2], t3 = mid[j1+3];
        #pragma unroll
        for (int j = 0; j < D; ++j)
            acc[j] += t0 * w2[j1*D + j]     + t1 * w2[(j1+1)*D + j]
                    + t2 * w2[(j1+2)*D + j] + t3 * w2[(j1+3)*D + j];
    }

    float* hrow = h + (size_t)n * D;
    #pragma unroll
    for (int j = 0; j < D; j += 4) {
        float4 v = { acc[j], acc[j+1], acc[j+2], acc[j+3] };
        *(float4*)(hrow + j) = v;
    }
}

// ---- sort step 1: per-chunk LDS histogram -> counts[chunk][bucket] ----
__global__ __launch_bounds__(256) void count_kernel(
    const int* __restrict__ ei, unsigned short* __restrict__ counts)
{
    __shared__ int s_hist[NBKT];
    const int blk = blockIdx.x, tid = threadIdx.x;
    const int* __restrict__ dst = ei + NE;
    for (int i = tid; i < NBKT; i += 256) s_hist[i] = 0;
    __syncthreads();
    for (int e = blk * 256 + tid; e < NE; e += CHUNKS * 256)
        atomicAdd(&s_hist[dst[e] / BN], 1);
    __syncthreads();
    for (int b = tid; b < NBKT; b += 256)
        counts[(size_t)blk * NBKT + b] = (unsigned short)s_hist[b];
}

// ---- sort step 2: per-bucket column scan over 1024 chunks (in place) --
__global__ __launch_bounds__(256) void scan_cols_kernel(
    unsigned short* __restrict__ counts, int* __restrict__ btotal)
{
    __shared__ int s[256];
    const int g = blockIdx.x, tid = threadIdx.x;
    int c[4];
    #pragma unroll
    for (int i = 0; i < 4; ++i)
        c[i] = counts[(size_t)(tid * 4 + i) * NBKT + g];
    int sum = c[0] + c[1] + c[2] + c[3];
    s[tid] = sum; __syncthreads();
    for (int off = 1; off < 256; off <<= 1) {
        int val = s[tid];
        int add = (tid >= off) ? s[tid - off] : 0;
        __syncthreads();
        s[tid] = val + add;
        __syncthreads();
    }
    int base = s[tid] - sum;            // exclusive across threads
    #pragma unroll
    for (int i = 0; i < 4; ++i) {
        counts[(size_t)(tid * 4 + i) * NBKT + g] = (unsigned short)base;
        base += c[i];
    }
    if (tid == 255) btotal[g] = s[255];
}

// ---- sort step 3: scan bucket totals -> offs[0..NBKT] ----------------
__global__ __launch_bounds__(1024) void scan_bsum_kernel(
    const int* __restrict__ btotal, int* __restrict__ offs)
{
    __shared__ int s[1024];
    const int tid = threadIdx.x;
    int b0 = 2 * tid, b1 = 2 * tid + 1;
    int v0 = (b0 < NBKT) ? btotal[b0] : 0;
    int v1 = (b1 < NBKT) ? btotal[b1] : 0;
    int sum = v0 + v1;
    s[tid] = sum; __syncthreads();
    for (int off = 1; off < 1024; off <<= 1) {
        int val = s[tid];
        int add = (tid >= off) ? s[tid - off] : 0;
        __syncthreads();
        s[tid] = val + add;
        __syncthreads();
    }
    int base = s[tid] - sum;
    if (b0 < NBKT) offs[b0] = base;
    if (b1 < NBKT) offs[b1] = base + v0;
    if (tid == 0)  offs[NBKT] = NE;
}

// ---- sort step 4: scatter packed (src<<6 | dst%64), LDS cursors ------
__global__ __launch_bounds__(256) void bin_kernel(
    const int* __restrict__ ei, const unsigned short* __restrict__ counts,
    const int* __restrict__ offs, int* __restrict__ packed)
{
    __shared__ int s_cur[NBKT];
    const int blk = blockIdx.x, tid = threadIdx.x;
    const int* __restrict__ dst = ei + NE;
    for (int b = tid; b < NBKT; b += 256)
        s_cur[b] = offs[b] + (int)counts[(size_t)blk * NBKT + b];
    __syncthreads();
    for (int e = blk * 256 + tid; e < NE; e += CHUNKS * 256) {
        int d = dst[e];
        int s = ei[e];
        int pos = atomicAdd(&s_cur[d / BN], 1);
        packed[pos] = (s << 6) | (d & (BN - 1));
    }
}

// ---- fused per-bucket node-sort (LDS) + wave-per-node aggregation ----
__global__ __launch_bounds__(256) void sortagg_kernel(
    const int* __restrict__ offs, const int* __restrict__ packed,
    const float* __restrict__ h, float* __restrict__ aggr)
{
    __shared__ int s_off[BN + 1];
    __shared__ int s_cur[BN];
    __shared__ int s_src[CAP];
    const int b = blockIdx.x, tid = threadIdx.x;
    const int start = offs[b], end = offs[b + 1];
    const int cnt = end - start;
    const int wid = tid >> 6, lane = tid & 63;
    const int base = b * BN;

    if (cnt <= CAP) {
        if (tid < BN) s_cur[tid] = 0;
        __syncthreads();
        for (int e = start + tid; e < end; e += 256)
            atomicAdd(&s_cur[packed[e] & (BN - 1)], 1);
        __syncthreads();
        if (tid < 64) {
            int v = s_cur[tid];
            int incl = v;
            #pragma unroll
            for (int off = 1; off < 64; off <<= 1) {
                int u = __shfl_up(incl, off, 64);
                if (tid >= off) incl += u;
            }
            s_off[tid] = incl - v;
            if (tid == 63) s_off[64] = cnt;
        }
        __syncthreads();
        if (tid < BN) s_cur[tid] = s_off[tid];
        __syncthreads();
        for (int e = start + tid; e < end; e += 256) {
            int p = packed[e];
            int pos = atomicAdd(&s_cur[p & (BN - 1)], 1);
            s_src[pos] = p >> 6;
        }
        __syncthreads();
        for (int m = wid; m < BN; m += 4) {
            int node = base + m;
            if (node < NN) {
                int s0 = s_off[m], s1 = s_off[m + 1];
                float a0=0,a1=0,a2=0,a3=0,a4=0,a5=0,a6=0,a7=0;
                int e = s0;
                for (; e + 8 <= s1; e += 8) {
                    int i0=s_src[e],  i1=s_src[e+1],i2=s_src[e+2],i3=s_src[e+3];
                    int i4=s_src[e+4],i5=s_src[e+5],i6=s_src[e+6],i7=s_src[e+7];
                    a0 += h[(size_t)i0*D+lane]; a1 += h[(size_t)i1*D+lane];
                    a2 += h[(size_t)i2*D+lane]; a3 += h[(size_t)i3*D+lane];
                    a4 += h[(size_t)i4*D+lane]; a5 += h[(size_t)i5*D+lane];
                    a6 += h[(size_t)i6*D+lane]; a7 += h[(size_t)i7*D+lane];
                }
                for (; e < s1; ++e) a0 += h[(size_t)s_src[e]*D+lane];
                aggr[(size_t)node*D+lane] = ((a0+a1)+(a2+a3))+((a4+a5)+(a6+a7));
            }
        }
    } else {
        for (int m = wid; m < BN; m += 4) {
            int node = base + m;
            if (node < NN) {
                float a = 0.f;
                for (int e = start; e < end; ++e) {
                    int p = packed[e];
                    if ((p & (BN - 1)) == m) a += h[(size_t)(p >> 6) * D + lane];
                }
                aggr[(size_t)node * D + lane] = a;
            }
        }
    }
}

// ---------------- legacy atomic aggregate (ws fallback) ----------------
__global__ __launch_bounds__(256) void aggregate_kernel(
    const int* __restrict__ ei, const float* __restrict__ h,
    float* __restrict__ aggr)
{
    int t = blockIdx.x * 256 + threadIdx.x;
    int e = t >> 6;
    int lane = t & 63;
    if (e >= NE) return;
    int src = ei[e];
    int dst = ei[NE + e];
    float v = h[(size_t)src * D + lane];
    atomicAdd(&aggr[(size_t)dst * D + lane], v);
}

// -------- update+decode via MFMA bf16 hi/lo (3 mfma per GEMM tile) -----
__global__ __launch_bounds__(256) void update_decode_mfma(
    const float* __restrict__ h, const float* __restrict__ aggr,
    const unsigned short* __restrict__ fragw,
    const float* __restrict__ wb1, const float* __restrict__ wb2,
    const float* __restrict__ db1, const float* __restrict__ dw2,
    const float* __restrict__ db2, float* __restrict__ out)
{
    __shared__ unsigned short midH[64 * 64];
    __shared__ unsigned short midL[64 * 64];
    const int tid = threadIdx.x;
    const int w = tid >> 6, l = tid & 63;
    const int q = l >> 4, c = l & 15;
    const int g0 = blockIdx.x * 64;
    const int rowbase = w * 16;

    union BU { uint4 u; s8b s; };

    s8b aH[2], aL[2];
    #pragma unroll
    for (int s = 0; s < 2; ++s) {
        const float* hp = h + (size_t)(g0 + rowbase + c) * D + s * 32 + q * 8;
        float4 f0 = *(const float4*)hp;
        float4 f1 = *(const float4*)(hp + 4);
        float fv[8] = {f0.x, f0.y, f0.z, f0.w, f1.x, f1.y, f1.z, f1.w};
        #pragma unroll
        for (int j = 0; j < 8; ++j) {
            unsigned short hh, ll;
            split_bf16(fv[j], hh, ll);
            aH[s][j] = (short)hh; aL[s][j] = (short)ll;
        }
    }

    f32x4 acc[4];
    #pragma unroll
    for (int t = 0; t < 4; ++t) acc[t] = (f32x4){0.f, 0.f, 0.f, 0.f};

    #pragma unroll
    for (int s = 0; s < 2; ++s) {
        #pragma unroll
        for (int t = 0; t < 4; ++t) {
            BU bh, bl;
            int fb = ((0 * 2 + s) * 4 + t) * 2;
            bh.u = *(const uint4*)&fragw[(size_t)fb * 512 + l * 8];
            bl.u = *(const uint4*)&fragw[(size_t)(fb + 1) * 512 + l * 8];
            acc[t] = __builtin_amdgcn_mfma_f32_16x16x32_bf16(aH[s], bh.s, acc[t], 0, 0, 0);
            acc[t] = __builtin_amdgcn_mfma_f32_16x16x32_bf16(aH[s], bl.s, acc[t], 0, 0, 0);
            acc[t] = __builtin_amdgcn_mfma_f32_16x16x32_bf16(aL[s], bh.s, acc[t], 0, 0, 0);
        }
    }

    #pragma unroll
    for (int t = 0; t < 4; ++t) {
        float bias = wb1[t * 16 + c];
        #pragma unroll
        for (int r = 0; r < 4; ++r) {
            int grow = rowbase + q * 4 + r;
            float v = gelu_exact(acc[t][r] + bias);
            unsigned short hh, ll;
            split_bf16(v, hh, ll);
            int byte = ((grow * 128 + (t * 16 + c) * 2)) ^ ((grow & 7) << 4);
            midH[byte >> 1] = hh; midL[byte >> 1] = ll;
        }
    }
    __syncthreads();

    #pragma unroll
    for (int s = 0; s < 2; ++s) {
        int ar = rowbase + c;
        int abyte = (ar * 128 + s * 64 + q * 16) ^ ((ar & 7) << 4);
        aH[s] = *(const s8b*)((const char*)midH + abyte);
        aL[s] = *(const s8b*)((const char*)midL + abyte);
    }
    #pragma unroll
    for (int t = 0; t < 4; ++t) acc[t] = (f32x4){0.f, 0.f, 0.f, 0.f};
    #pragma unroll
    for (int s = 0; s < 2; ++s) {
        #pragma unroll
        for (int t = 0; t < 4; ++t) {
            BU bh, bl;
            int fb = ((1 * 2 + s) * 4 + t) * 2;
            bh.u = *(const uint4*)&fragw[(size_t)fb * 512 + l * 8];
            bl.u = *(const uint4*)&fragw[(size_t)(fb + 1) * 512 + l * 8];
            acc[t] = __builtin_amdgcn_mfma_f32_16x16x32_bf16(aH[s], bh.s, acc[t], 0, 0, 0);
            acc[t] = __builtin_amdgcn_mfma_f32_16x16x32_bf16(aH[s], bl.s, acc[t], 0, 0, 0);
            acc[t] = __builtin_amdgcn_mfma_f32_16x16x32_bf16(aL[s], bh.s, acc[t], 0, 0, 0);
        }
    }
    __syncthreads();

    #pragma unroll
    for (int t = 0; t < 4; ++t) {
        float bias = wb2[t * 16 + c];
        #pragma unroll
        for (int r = 0; r < 4; ++r) {
            int grow = rowbase + q * 4 + r;
            float ag = aggr[(size_t)(g0 + grow) * D + t * 16 + c];
            float v = gelu_exact(acc[t][r] + bias + ag);
            unsigned short hh, ll;
            split_bf16(v, hh, ll);
            int byte = ((grow * 128 + (t * 16 + c) * 2)) ^ ((grow & 7) << 4);
            midH[byte >> 1] = hh; midL[byte >> 1] = ll;
        }
    }
    __syncthreads();

    #pragma unroll
    for (int s = 0; s < 2; ++s) {
        int ar = rowbase + c;
        int abyte = (ar * 128 + s * 64 + q * 16) ^ ((ar & 7) << 4);
        aH[s] = *(const s8b*)((const char*)midH + abyte);
        aL[s] = *(const s8b*)((const char*)midL + abyte);
    }
    #pragma unroll
    for (int t = 0; t < 4; ++t) acc[t] = (f32x4){0.f, 0.f, 0.f, 0.f};
    #pragma unroll
    for (int s = 0; s < 2; ++s) {
        #pragma unroll
        for (int t = 0; t < 4; ++t) {
            BU bh, bl;
            int fb = ((2 * 2 + s) * 4 + t) * 2;
            bh.u = *(const uint4*)&fragw[(size_t)fb * 512 + l * 8];
            bl.u = *(const uint4*)&fragw[(size_t)(fb + 1) * 512 + l * 8];
            acc[t] = __builtin_amdgcn_mfma_f32_16x16x32_bf16(aH[s], bh.s, acc[t], 0, 0, 0);
            acc[t] = __builtin_amdgcn_mfma_f32_16x16x32_bf16(aH[s], bl.s, acc[t], 0, 0, 0);
            acc[t] = __builtin_amdgcn_mfma_f32_16x16x32_bf16(aL[s], bh.s, acc[t], 0, 0, 0);
        }
    }

    float p[4] = {0.f, 0.f, 0.f, 0.f};
    #pragma unroll
    for (int t = 0; t < 4; ++t) {
        float bias = db1[t * 16 + c];
        float wv = dw2[t * 16 + c];
        #pragma unroll
        for (int r = 0; r < 4; ++r)
            p[r] += gelu_exact(acc[t][r] + bias) * wv;
    }
    #pragma unroll
    for (int m = 1; m < 16; m <<= 1) {
        #pragma unroll
        for (int r = 0; r < 4; ++r) p[r] += __shfl_xor(p[r], m, 16);
    }
    if (c == 0) {
        float b2v = db2[0];
        #pragma unroll
        for (int r = 0; r < 4; ++r) {
            int row = g0 + rowbase + q * 4 + r;
            if (row < NN) out[row] = p[r] + b2v;
        }
    }
}

// ------- legacy VALU update (ws fallback) ------------------------------
__global__ __launch_bounds__(256) void update_decode_valu(
    const float* __restrict__ h, const float* __restrict__ aggr,
    const float* __restrict__ ww1, const float* __restrict__ wb1,
    const float* __restrict__ ww2, const float* __restrict__ wb2,
    const float* __restrict__ dw1, const float* __restrict__ db1,
    const float* __restrict__ dw2, const float* __restrict__ db2,
    float* __restrict__ out)
{
    int n = blockIdx.x * 256 + threadIdx.x;
    if (n >= NN) return;
    float hrow[D];
    #pragma unroll
    for (int j = 0; j < D; j += 4) {
        float4 v = *(const float4*)(h + (size_t)n * D + j);
        hrow[j] = v.x; hrow[j+1] = v.y; hrow[j+2] = v.z; hrow[j+3] = v.w;
    }
    float mid[D];
    for (int j1 = 0; j1 < D; j1 += 4) {
        float a0 = wb1[j1], a1 = wb1[j1+1], a2 = wb1[j1+2], a3 = wb1[j1+3];
        #pragma unroll
        for (int k = 0; k < D; ++k) {
            float t = hrow[k];
            a0 += t * ww1[k*D + j1];   a1 += t * ww1[k*D + j1+1];
            a2 += t * ww1[k*D + j1+2]; a3 += t * ww1[k*D + j1+3];
        }
        mid[j1]=gelu_exact(a0); mid[j1+1]=gelu_exact(a1);
        mid[j1+2]=gelu_exact(a2); mid[j1+3]=gelu_exact(a3);
    }
    #pragma unroll
    for (int j = 0; j < D; j += 4) {
        float4 v = *(const float4*)(aggr + (size_t)n * D + j);
        hrow[j]=wb2[j]+v.x; hrow[j+1]=wb2[j+1]+v.y;
        hrow[j+2]=wb2[j+2]+v.z; hrow[j+3]=wb2[j+3]+v.w;
    }
    for (int j1 = 0; j1 < D; j1 += 4) {
        float t0=mid[j1], t1=mid[j1+1], t2=mid[j1+2], t3=mid[j1+3];
        #pragma unroll
        for (int j = 0; j < D; ++j)
            hrow[j] += t0*ww2[j1*D+j] + t1*ww2[(j1+1)*D+j]
                     + t2*ww2[(j1+2)*D+j] + t3*ww2[(j1+3)*D+j];
    }
    #pragma unroll
    for (int j = 0; j < D; ++j) hrow[j] = gelu_exact(hrow[j]);
    float o = db2[0];
    for (int j1 = 0; j1 < D; j1 += 4) {
        float a0 = db1[j1], a1 = db1[j1+1], a2 = db1[j1+2], a3 = db1[j1+3];
        #pragma unroll
        for (int k = 0; k < D; ++k) {
            float t = hrow[k];
            a0 += t*dw1[k*D+j1];   a1 += t*dw1[k*D+j1+1];
            a2 += t*dw1[k*D+j1+2]; a3 += t*dw1[k*D+j1+3];
        }
        o += gelu_exact(a0)*dw2[j1] + gelu_exact(a1)*dw2[j1+1]
           + gelu_exact(a2)*dw2[j1+2] + gelu_exact(a3)*dw2[j1+3];
    }
    out[n] = o;
}

extern "C" void kernel_launch(void* const* d_in, const int* in_sizes, int n_in,
                              void* d_out, int out_size, void* d_ws, size_t ws_size,
                              hipStream_t stream) {
    const float* x    = (const float*)d_in[0];
    const float* grid = (const float*)d_in[1];
    const int*   ei   = (const int*)d_in[2];
    const float* p_w1 = (const float*)d_in[4];
    const float* p_b1 = (const float*)d_in[5];
    const float* p_w2 = (const float*)d_in[6];
    const float* p_b2 = (const float*)d_in[7];
    const float* w_w1 = (const float*)d_in[8];
    const float* w_b1 = (const float*)d_in[9];
    const float* w_w2 = (const float*)d_in[10];
    const float* w_b2 = (const float*)d_in[11];
    const float* d_w1 = (const float*)d_in[12];
    const float* d_b1 = (const float*)d_in[13];
    const float* d_w2 = (const float*)d_in[14];
    const float* d_b2 = (const float*)d_in[15];
    float* out = (float*)d_out;

    float* h    = (float*)d_ws;                            // [NN, D] f32
    float* aggr = h + (size_t)NN * D;                      // [NN, D] f32
    unsigned short* counts = (unsigned short*)(aggr + (size_t)NN * D); // [CHUNKS][NBKT] u16
    int* btotal = (int*)(counts + (size_t)CHUNKS * NBKT);  // [NBKT]
    int* offs   = btotal + NBKT;                           // [NBKT+1]
    int* packed = offs + NBKT + 1;                         // [NE]
    unsigned short* fragw =
        (unsigned short*)((((uintptr_t)(packed + NE)) + 15) & ~(uintptr_t)15); // [NFRAG*512] u16

    size_t need = ((char*)(fragw + NFRAG * 512)) - (char*)d_ws;

    if (ws_size >= need) {
        pack_frags_kernel<<<(NFRAG * 64 + 255) / 256, 256, 0, stream>>>(
            w_w1, w_w2, d_w1, p_w1, p_w2, fragw);
        project_mfma<<<(NN + 63) / 64, 256, 0, stream>>>(
            x, grid, fragw, p_b1, p_b2, h);
        count_kernel    <<<CHUNKS, 256, 0, stream>>>(ei, counts);
        scan_cols_kernel<<<NBKT,   256, 0, stream>>>(counts, btotal);
        scan_bsum_kernel<<<1,     1024, 0, stream>>>(btotal, offs);
        bin_kernel      <<<CHUNKS, 256, 0, stream>>>(ei, counts, offs, packed);
        sortagg_kernel  <<<NBKT,   256, 0, stream>>>(offs, packed, h, aggr);
        update_decode_mfma<<<(NN + 63) / 64, 256, 0, stream>>>(
            h, aggr, fragw, w_b1, w_b2, d_b1, d_w2, d_b2, out);
    } else {
        project_kernel<<<(NN + 255) / 256, 256, 0, stream>>>(
            x, grid, p_w1, p_b1, p_w2, p_b2, h);
        hipMemsetAsync(aggr, 0, (size_t)NN * D * sizeof(float), stream);
        aggregate_kernel<<<(size_t)NE * 64 / 256, 256, 0, stream>>>(ei, h, aggr);
        update_decode_valu<<<(NN + 255) / 256, 256, 0, stream>>>(
            h, aggr, w_w1, w_b1, w_w2, w_b2, d_w1, d_b1, d_w2, d_b2, out);
    }
}

// Round 12
// 170.542 us; speedup vs baseline: 1.0820x; 1.0094x over previous
//
#include <hip/hip_runtime.h>
#include <math.h>

#define NN 100000
#define NE 1600000
#define D 64
#define INDIM 18
#define NCHK 256              // blocks for count/bin
#define BN 64                 // nodes per bucket (sort)
#define NBKT 1563             // ceil(NN / BN)
#define CAP 1536              // LDS edge capacity per bucket
#define NFRAG 72              // 48 update frags + 8 p_w1 + 16 p_w2

typedef __attribute__((ext_vector_type(8))) short s8b;    // 8 bf16 (4 VGPR)
typedef __attribute__((ext_vector_type(4))) float f32x4;  // MFMA acc

__device__ __forceinline__ float gelu_exact(float x) {
    return 0.5f * x * (1.0f + erff(x * 0.70710678118654752f));
}

// split f32 into bf16 hi + bf16 lo (round-to-nearest-even)
__device__ __forceinline__ void split_bf16(float f, unsigned short& h, unsigned short& l) {
    unsigned int u = __float_as_uint(f);
    unsigned int hb = (u + 0x7FFFu + ((u >> 16) & 1u)) >> 16;
    float hf = __uint_as_float(hb << 16);
    float lo = f - hf;
    unsigned int u2 = __float_as_uint(lo);
    unsigned int lb = (u2 + 0x7FFFu + ((u2 >> 16) & 1u)) >> 16;
    h = (unsigned short)hb; l = (unsigned short)lb;
}

// ---- pack B-fragments (hi/lo bf16, lane-major) ------------------------
__global__ __launch_bounds__(256) void pack_frags_kernel(
    const float* __restrict__ ww1, const float* __restrict__ ww2,
    const float* __restrict__ dw1, const float* __restrict__ pw1,
    const float* __restrict__ pw2, unsigned short* __restrict__ fragw)
{
    int tid = blockIdx.x * 256 + threadIdx.x;
    if (tid >= NFRAG * 64) return;
    int f = tid >> 6, l = tid & 63;
    unsigned short o[8];
    if (f < 48) {
        int x = f & 1, t = (f >> 1) & 3, s = (f >> 3) & 1, layer = f >> 4;
        const float* W = (layer == 0) ? ww1 : ((layer == 1) ? ww2 : dw1);
        #pragma unroll
        for (int j = 0; j < 8; ++j) {
            int k = s * 32 + (l >> 4) * 8 + j;
            int n = t * 16 + (l & 15);
            unsigned short hh, ll;
            split_bf16(W[k * D + n], hh, ll);
            o[j] = x ? ll : hh;
        }
    } else if (f < 56) {
        int g = f - 48, x = g & 1, t = (g >> 1) & 3;
        #pragma unroll
        for (int j = 0; j < 8; ++j) {
            int k = (l >> 4) * 8 + j;
            int n = t * 16 + (l & 15);
            float v = (k < INDIM) ? pw1[k * D + n] : 0.f;
            unsigned short hh, ll;
            split_bf16(v, hh, ll);
            o[j] = x ? ll : hh;
        }
    } else {
        int g = f - 56, x = g & 1, t = (g >> 1) & 3, s = (g >> 3) & 1;
        #pragma unroll
        for (int j = 0; j < 8; ++j) {
            int k = s * 32 + (l >> 4) * 8 + j;
            int n = t * 16 + (l & 15);
            unsigned short hh, ll;
            split_bf16(pw2[k * D + n], hh, ll);
            o[j] = x ? ll : hh;
        }
    }
    uint4 v;
    v.x = (unsigned)o[0] | ((unsigned)o[1] << 16);
    v.y = (unsigned)o[2] | ((unsigned)o[3] << 16);
    v.z = (unsigned)o[4] | ((unsigned)o[5] << 16);
    v.w = (unsigned)o[6] | ((unsigned)o[7] << 16);
    *(uint4*)&fragw[(size_t)f * 512 + l * 8] = v;
}

// -------- project via MFMA: h = (concat(x,grid) @ w1 ..gelu..) @ w2 + b2
__global__ __launch_bounds__(256) void project_mfma(
    const float* __restrict__ x, const float* __restrict__ grid,
    const unsigned short* __restrict__ fragw,
    const float* __restrict__ pb1, const float* __restrict__ pb2,
    float* __restrict__ h)
{
    __shared__ unsigned short midH[64 * 64];
    __shared__ unsigned short midL[64 * 64];
    const int tid = threadIdx.x;
    const int w = tid >> 6, l = tid & 63;
    const int q = l >> 4, c = l & 15;
    const int g0 = blockIdx.x * 64;
    const int rowbase = w * 16;

    union BU { uint4 u; s8b s; };

    const int arow = g0 + rowbase + c;
    const bool ok = arow < NN;
    float fv[8] = {0.f,0.f,0.f,0.f,0.f,0.f,0.f,0.f};
    if (q < 2) {
        if (ok) {
            const float* xp = x + (size_t)arow * 16 + q * 8;
            float4 f0 = *(const float4*)xp;
            float4 f1 = *(const float4*)(xp + 4);
            fv[0]=f0.x; fv[1]=f0.y; fv[2]=f0.z; fv[3]=f0.w;
            fv[4]=f1.x; fv[5]=f1.y; fv[6]=f1.z; fv[7]=f1.w;
        }
    } else if (q == 2) {
        if (ok) {
            float2 g2 = *(const float2*)(grid + (size_t)arow * 2);
            fv[0] = g2.x; fv[1] = g2.y;
        }
    }
    s8b aH[2], aL[2];
    #pragma unroll
    for (int j = 0; j < 8; ++j) {
        unsigned short hh, ll;
        split_bf16(fv[j], hh, ll);
        aH[0][j] = (short)hh; aL[0][j] = (short)ll;
    }

    f32x4 acc[4];
    #pragma unroll
    for (int t = 0; t < 4; ++t) acc[t] = (f32x4){0.f, 0.f, 0.f, 0.f};
    #pragma unroll
    for (int t = 0; t < 4; ++t) {
        BU bh, bl;
        int fb = 48 + t * 2;
        bh.u = *(const uint4*)&fragw[(size_t)fb * 512 + l * 8];
        bl.u = *(const uint4*)&fragw[(size_t)(fb + 1) * 512 + l * 8];
        acc[t] = __builtin_amdgcn_mfma_f32_16x16x32_bf16(aH[0], bh.s, acc[t], 0, 0, 0);
        acc[t] = __builtin_amdgcn_mfma_f32_16x16x32_bf16(aH[0], bl.s, acc[t], 0, 0, 0);
        acc[t] = __builtin_amdgcn_mfma_f32_16x16x32_bf16(aL[0], bh.s, acc[t], 0, 0, 0);
    }

    #pragma unroll
    for (int t = 0; t < 4; ++t) {
        float bias = pb1[t * 16 + c];
        #pragma unroll
        for (int r = 0; r < 4; ++r) {
            int grow = rowbase + q * 4 + r;
            float v = gelu_exact(acc[t][r] + bias);
            unsigned short hh, ll;
            split_bf16(v, hh, ll);
            int byte = ((grow * 128 + (t * 16 + c) * 2)) ^ ((grow & 7) << 4);
            midH[byte >> 1] = hh; midL[byte >> 1] = ll;
        }
    }
    __syncthreads();

    #pragma unroll
    for (int s = 0; s < 2; ++s) {
        int ar = rowbase + c;
        int abyte = (ar * 128 + s * 64 + q * 16) ^ ((ar & 7) << 4);
        aH[s] = *(const s8b*)((const char*)midH + abyte);
        aL[s] = *(const s8b*)((const char*)midL + abyte);
    }
    #pragma unroll
    for (int t = 0; t < 4; ++t) acc[t] = (f32x4){0.f, 0.f, 0.f, 0.f};
    #pragma unroll
    for (int s = 0; s < 2; ++s) {
        #pragma unroll
        for (int t = 0; t < 4; ++t) {
            BU bh, bl;
            int fb = 56 + s * 8 + t * 2;
            bh.u = *(const uint4*)&fragw[(size_t)fb * 512 + l * 8];
            bl.u = *(const uint4*)&fragw[(size_t)(fb + 1) * 512 + l * 8];
            acc[t] = __builtin_amdgcn_mfma_f32_16x16x32_bf16(aH[s], bh.s, acc[t], 0, 0, 0);
            acc[t] = __builtin_amdgcn_mfma_f32_16x16x32_bf16(aH[s], bl.s, acc[t], 0, 0, 0);
            acc[t] = __builtin_amdgcn_mfma_f32_16x16x32_bf16(aL[s], bh.s, acc[t], 0, 0, 0);
        }
    }
    #pragma unroll
    for (int t = 0; t < 4; ++t) {
        float bias = pb2[t * 16 + c];
        #pragma unroll
        for (int r = 0; r < 4; ++r) {
            int row = g0 + rowbase + q * 4 + r;
            if (row < NN) h[(size_t)row * D + t * 16 + c] = acc[t][r] + bias;
        }
    }
}

// ---------------- project VALU (ws fallback) ---------------------------
__global__ __launch_bounds__(256) void project_kernel(
    const float* __restrict__ x, const float* __restrict__ grid,
    const float* __restrict__ w1, const float* __restrict__ b1,
    const float* __restrict__ w2, const float* __restrict__ b2,
    float* __restrict__ h)
{
    int n = blockIdx.x * 256 + threadIdx.x;
    if (n >= NN) return;

    float in[INDIM];
    {
        const float4* xr = (const float4*)(x + (size_t)n * 16);
        float4 a = xr[0], b = xr[1], c = xr[2], d = xr[3];
        in[0]=a.x; in[1]=a.y; in[2]=a.z; in[3]=a.w;
        in[4]=b.x; in[5]=b.y; in[6]=b.z; in[7]=b.w;
        in[8]=c.x; in[9]=c.y; in[10]=c.z; in[11]=c.w;
        in[12]=d.x; in[13]=d.y; in[14]=d.z; in[15]=d.w;
        float2 g = *(const float2*)(grid + (size_t)n * 2);
        in[16]=g.x; in[17]=g.y;
    }

    float mid[D];
    for (int j1 = 0; j1 < D; j1 += 4) {
        float a0 = b1[j1], a1 = b1[j1+1], a2 = b1[j1+2], a3 = b1[j1+3];
        #pragma unroll
        for (int k = 0; k < INDIM; ++k) {
            float t = in[k];
            a0 += t * w1[k*D + j1];
            a1 += t * w1[k*D + j1+1];
            a2 += t * w1[k*D + j1+2];
            a3 += t * w1[k*D + j1+3];
        }
        mid[j1]   = gelu_exact(a0);
        mid[j1+1] = gelu_exact(a1);
        mid[j1+2] = gelu_exact(a2);
        mid[j1+3] = gelu_exact(a3);
    }

    float acc[D];
    #pragma unroll
    for (int j = 0; j < D; ++j) acc[j] = b2[j];
    for (int j1 = 0; j1 < D; j1 += 4) {
        float t0 = mid[j1], t1 = mid[j1+1], t2 = mid[j1+2], t3 = mid[j1+3];
        #pragma unroll
        for (int j = 0; j < D; ++j)
            acc[j] += t0 * w2[j1*D + j]     + t1 * w2[(j1+1)*D + j]
                    + t2 * w2[(j1+2)*D + j] + t3 * w2[(j1+3)*D + j];
    }

    float* hrow = h + (size_t)n * D;
    #pragma unroll
    for (int j = 0; j < D; j += 4) {
        float4 v = { acc[j], acc[j+1], acc[j+2], acc[j+3] };
        *(float4*)(hrow + j) = v;
    }
}

// ---- sort step 1: per-block LDS histogram -> global deg[bucket] ------
__global__ __launch_bounds__(256) void count_kernel(
    const int* __restrict__ ei, int* __restrict__ deg)
{
    __shared__ int s_hist[NBKT];
    const int blk = blockIdx.x, tid = threadIdx.x;
    const int* __restrict__ dst = ei + NE;
    for (int i = tid; i < NBKT; i += 256) s_hist[i] = 0;
    __syncthreads();
    for (int e = blk * 256 + tid; e < NE; e += NCHK * 256)
        atomicAdd(&s_hist[dst[e] / BN], 1);
    __syncthreads();
    for (int b = tid; b < NBKT; b += 256) {
        int c = s_hist[b];
        if (c) atomicAdd(&deg[b], c);
    }
}

// ---- sort step 2: scan bucket totals -> offs[0..NBKT], init cursor ----
__global__ __launch_bounds__(1024) void scan_bsum_kernel(
    const int* __restrict__ deg, int* __restrict__ offs, int* __restrict__ cursor)
{
    __shared__ int s[1024];
    const int tid = threadIdx.x;
    int b0 = 2 * tid, b1 = 2 * tid + 1;
    int v0 = (b0 < NBKT) ? deg[b0] : 0;
    int v1 = (b1 < NBKT) ? deg[b1] : 0;
    int sum = v0 + v1;
    s[tid] = sum; __syncthreads();
    for (int off = 1; off < 1024; off <<= 1) {
        int val = s[tid];
        int add = (tid >= off) ? s[tid - off] : 0;
        __syncthreads();
        s[tid] = val + add;
        __syncthreads();
    }
    int base = s[tid] - sum;
    if (b0 < NBKT) { offs[b0] = base;      cursor[b0] = base; }
    if (b1 < NBKT) { offs[b1] = base + v0; cursor[b1] = base + v0; }
    if (tid == 0)  offs[NBKT] = NE;
}

// ---- sort step 3: reserve ranges + scatter (src<<6 | dst%64) ---------
// Each block: LDS hist -> atomic range reservation per bucket -> LDS-cursor
// scatter into its own contiguous sub-regions (single-writer lines).
__global__ __launch_bounds__(256) void bin_reserve_kernel(
    const int* __restrict__ ei, int* __restrict__ cursor,
    int* __restrict__ packed)
{
    __shared__ int s_cur[NBKT];
    const int blk = blockIdx.x, tid = threadIdx.x;
    const int* __restrict__ dst = ei + NE;
    for (int i = tid; i < NBKT; i += 256) s_cur[i] = 0;
    __syncthreads();
    for (int e = blk * 256 + tid; e < NE; e += NCHK * 256)
        atomicAdd(&s_cur[dst[e] / BN], 1);
    __syncthreads();
    for (int b = tid; b < NBKT; b += 256) {
        int c = s_cur[b];
        s_cur[b] = c ? atomicAdd(&cursor[b], c) : 0;
    }
    __syncthreads();
    for (int e = blk * 256 + tid; e < NE; e += NCHK * 256) {
        int d = dst[e];
        int s = ei[e];
        int pos = atomicAdd(&s_cur[d / BN], 1);
        packed[pos] = (s << 6) | (d & (BN - 1));
    }
}

// ---- fused per-bucket node-sort (LDS) + wave-per-node aggregation ----
__global__ __launch_bounds__(256) void sortagg_kernel(
    const int* __restrict__ offs, const int* __restrict__ packed,
    const float* __restrict__ h, float* __restrict__ aggr)
{
    __shared__ int s_off[BN + 1];
    __shared__ int s_cur[BN];
    __shared__ int s_src[CAP];
    const int b = blockIdx.x, tid = threadIdx.x;
    const int start = offs[b], end = offs[b + 1];
    const int cnt = end - start;
    const int wid = tid >> 6, lane = tid & 63;
    const int base = b * BN;

    if (cnt <= CAP) {
        if (tid < BN) s_cur[tid] = 0;
        __syncthreads();
        for (int e = start + tid; e < end; e += 256)
            atomicAdd(&s_cur[packed[e] & (BN - 1)], 1);
        __syncthreads();
        if (tid < 64) {
            int v = s_cur[tid];
            int incl = v;
            #pragma unroll
            for (int off = 1; off < 64; off <<= 1) {
                int u = __shfl_up(incl, off, 64);
                if (tid >= off) incl += u;
            }
            s_off[tid] = incl - v;
            if (tid == 63) s_off[64] = cnt;
        }
        __syncthreads();
        if (tid < BN) s_cur[tid] = s_off[tid];
        __syncthreads();
        for (int e = start + tid; e < end; e += 256) {
            int p = packed[e];
            int pos = atomicAdd(&s_cur[p & (BN - 1)], 1);
            s_src[pos] = p >> 6;
        }
        __syncthreads();
        for (int m = wid; m < BN; m += 4) {
            int node = base + m;
            if (node < NN) {
                int s0 = s_off[m], s1 = s_off[m + 1];
                float a0=0,a1=0,a2=0,a3=0,a4=0,a5=0,a6=0,a7=0;
                int e = s0;
                for (; e + 8 <= s1; e += 8) {
                    int i0=s_src[e],  i1=s_src[e+1],i2=s_src[e+2],i3=s_src[e+3];
                    int i4=s_src[e+4],i5=s_src[e+5],i6=s_src[e+6],i7=s_src[e+7];
                    a0 += h[(size_t)i0*D+lane]; a1 += h[(size_t)i1*D+lane];
                    a2 += h[(size_t)i2*D+lane]; a3 += h[(size_t)i3*D+lane];
                    a4 += h[(size_t)i4*D+lane]; a5 += h[(size_t)i5*D+lane];
                    a6 += h[(size_t)i6*D+lane]; a7 += h[(size_t)i7*D+lane];
                }
                for (; e < s1; ++e) a0 += h[(size_t)s_src[e]*D+lane];
                aggr[(size_t)node*D+lane] = ((a0+a1)+(a2+a3))+((a4+a5)+(a6+a7));
            }
        }
    } else {
        for (int m = wid; m < BN; m += 4) {
            int node = base + m;
            if (node < NN) {
                float a = 0.f;
                for (int e = start; e < end; ++e) {
                    int p = packed[e];
                    if ((p & (BN - 1)) == m) a += h[(size_t)(p >> 6) * D + lane];
                }
                aggr[(size_t)node * D + lane] = a;
            }
        }
    }
}

// ---------------- legacy atomic aggregate (ws fallback) ----------------
__global__ __launch_bounds__(256) void aggregate_kernel(
    const int* __restrict__ ei, const float* __restrict__ h,
    float* __restrict__ aggr)
{
    int t = blockIdx.x * 256 + threadIdx.x;
    int e = t >> 6;
    int lane = t & 63;
    if (e >= NE) return;
    int src = ei[e];
    int dst = ei[NE + e];
    float v = h[(size_t)src * D + lane];
    atomicAdd(&aggr[(size_t)dst * D + lane], v);
}

// -------- update+decode via MFMA bf16 hi/lo (3 mfma per GEMM tile) -----
__global__ __launch_bounds__(256) void update_decode_mfma(
    const float* __restrict__ h, const float* __restrict__ aggr,
    const unsigned short* __restrict__ fragw,
    const float* __restrict__ wb1, const float* __restrict__ wb2,
    const float* __restrict__ db1, const float* __restrict__ dw2,
    const float* __restrict__ db2, float* __restrict__ out)
{
    __shared__ unsigned short midH[64 * 64];
    __shared__ unsigned short midL[64 * 64];
    const int tid = threadIdx.x;
    const int w = tid >> 6, l = tid & 63;
    const int q = l >> 4, c = l & 15;
    const int g0 = blockIdx.x * 64;
    const int rowbase = w * 16;

    union BU { uint4 u; s8b s; };

    s8b aH[2], aL[2];
    #pragma unroll
    for (int s = 0; s < 2; ++s) {
        const float* hp = h + (size_t)(g0 + rowbase + c) * D + s * 32 + q * 8;
        float4 f0 = *(const float4*)hp;
        float4 f1 = *(const float4*)(hp + 4);
        float fv[8] = {f0.x, f0.y, f0.z, f0.w, f1.x, f1.y, f1.z, f1.w};
        #pragma unroll
        for (int j = 0; j < 8; ++j) {
            unsigned short hh, ll;
            split_bf16(fv[j], hh, ll);
            aH[s][j] = (short)hh; aL[s][j] = (short)ll;
        }
    }

    f32x4 acc[4];
    #pragma unroll
    for (int t = 0; t < 4; ++t) acc[t] = (f32x4){0.f, 0.f, 0.f, 0.f};

    #pragma unroll
    for (int s = 0; s < 2; ++s) {
        #pragma unroll
        for (int t = 0; t < 4; ++t) {
            BU bh, bl;
            int fb = ((0 * 2 + s) * 4 + t) * 2;
            bh.u = *(const uint4*)&fragw[(size_t)fb * 512 + l * 8];
            bl.u = *(const uint4*)&fragw[(size_t)(fb + 1) * 512 + l * 8];
            acc[t] = __builtin_amdgcn_mfma_f32_16x16x32_bf16(aH[s], bh.s, acc[t], 0, 0, 0);
            acc[t] = __builtin_amdgcn_mfma_f32_16x16x32_bf16(aH[s], bl.s, acc[t], 0, 0, 0);
            acc[t] = __builtin_amdgcn_mfma_f32_16x16x32_bf16(aL[s], bh.s, acc[t], 0, 0, 0);
        }
    }

    #pragma unroll
    for (int t = 0; t < 4; ++t) {
        float bias = wb1[t * 16 + c];
        #pragma unroll
        for (int r = 0; r < 4; ++r) {
            int grow = rowbase + q * 4 + r;
            float v = gelu_exact(acc[t][r] + bias);
            unsigned short hh, ll;
            split_bf16(v, hh, ll);
            int byte = ((grow * 128 + (t * 16 + c) * 2)) ^ ((grow & 7) << 4);
            midH[byte >> 1] = hh; midL[byte >> 1] = ll;
        }
    }
    __syncthreads();

    #pragma unroll
    for (int s = 0; s < 2; ++s) {
        int ar = rowbase + c;
        int abyte = (ar * 128 + s * 64 + q * 16) ^ ((ar & 7) << 4);
        aH[s] = *(const s8b*)((const char*)midH + abyte);
        aL[s] = *(const s8b*)((const char*)midL + abyte);
    }
    #pragma unroll
    for (int t = 0; t < 4; ++t) acc[t] = (f32x4){0.f, 0.f, 0.f, 0.f};
    #pragma unroll
    for (int s = 0; s < 2; ++s) {
        #pragma unroll
        for (int t = 0; t < 4; ++t) {
            BU bh, bl;
            int fb = ((1 * 2 + s) * 4 + t) * 2;
            bh.u = *(const uint4*)&fragw[(size_t)fb * 512 + l * 8];
            bl.u = *(const uint4*)&fragw[(size_t)(fb + 1) * 512 + l * 8];
            acc[t] = __builtin_amdgcn_mfma_f32_16x16x32_bf16(aH[s], bh.s, acc[t], 0, 0, 0);
            acc[t] = __builtin_amdgcn_mfma_f32_16x16x32_bf16(aH[s], bl.s, acc[t], 0, 0, 0);
            acc[t] = __builtin_amdgcn_mfma_f32_16x16x32_bf16(aL[s], bh.s, acc[t], 0, 0, 0);
        }
    }
    __syncthreads();

    #pragma unroll
    for (int t = 0; t < 4; ++t) {
        float bias = wb2[t * 16 + c];
        #pragma unroll
        for (int r = 0; r < 4; ++r) {
            int grow = rowbase + q * 4 + r;
            float ag = aggr[(size_t)(g0 + grow) * D + t * 16 + c];
            float v = gelu_exact(acc[t][r] + bias + ag);
            unsigned short hh, ll;
            split_bf16(v, hh, ll);
            int byte = ((grow * 128 + (t * 16 + c) * 2)) ^ ((grow & 7) << 4);
            midH[byte >> 1] = hh; midL[byte >> 1] = ll;
        }
    }
    __syncthreads();

    #pragma unroll
    for (int s = 0; s < 2; ++s) {
        int ar = rowbase + c;
        int abyte = (ar * 128 + s * 64 + q * 16) ^ ((ar & 7) << 4);
        aH[s] = *(const s8b*)((const char*)midH + abyte);
        aL[s] = *(const s8b*)((const char*)midL + abyte);
    }
    #pragma unroll
    for (int t = 0; t < 4; ++t) acc[t] = (f32x4){0.f, 0.f, 0.f, 0.f};
    #pragma unroll
    for (int s = 0; s < 2; ++s) {
        #pragma unroll
        for (int t = 0; t < 4; ++t) {
            BU bh, bl;
            int fb = ((2 * 2 + s) * 4 + t) * 2;
            bh.u = *(const uint4*)&fragw[(size_t)fb * 512 + l * 8];
            bl.u = *(const uint4*)&fragw[(size_t)(fb + 1) * 512 + l * 8];
            acc[t] = __builtin_amdgcn_mfma_f32_16x16x32_bf16(aH[s], bh.s, acc[t], 0, 0, 0);
            acc[t] = __builtin_amdgcn_mfma_f32_16x16x32_bf16(aH[s], bl.s, acc[t], 0, 0, 0);
            acc[t] = __builtin_amdgcn_mfma_f32_16x16x32_bf16(aL[s], bh.s, acc[t], 0, 0, 0);
        }
    }

    float p[4] = {0.f, 0.f, 0.f, 0.f};
    #pragma unroll
    for (int t = 0; t < 4; ++t) {
        float bias = db1[t * 16 + c];
        float wv = dw2[t * 16 + c];
        #pragma unroll
        for (int r = 0; r < 4; ++r)
            p[r] += gelu_exact(acc[t][r] + bias) * wv;
    }
    #pragma unroll
    for (int m = 1; m < 16; m <<= 1) {
        #pragma unroll
        for (int r = 0; r < 4; ++r) p[r] += __shfl_xor(p[r], m, 16);
    }
    if (c == 0) {
        float b2v = db2[0];
        #pragma unroll
        for (int r = 0; r < 4; ++r) {
            int row = g0 + rowbase + q * 4 + r;
            if (row < NN) out[row] = p[r] + b2v;
        }
    }
}

// ------- legacy VALU update (ws fallback) ------------------------------
__global__ __launch_bounds__(256) void update_decode_valu(
    const float* __restrict__ h, const float* __restrict__ aggr,
    const float* __restrict__ ww1, const float* __restrict__ wb1,
    const float* __restrict__ ww2, const float* __restrict__ wb2,
    const float* __restrict__ dw1, const float* __restrict__ db1,
    const float* __restrict__ dw2, const float* __restrict__ db2,
    float* __restrict__ out)
{
    int n = blockIdx.x * 256 + threadIdx.x;
    if (n >= NN) return;
    float hrow[D];
    #pragma unroll
    for (int j = 0; j < D; j += 4) {
        float4 v = *(const float4*)(h + (size_t)n * D + j);
        hrow[j] = v.x; hrow[j+1] = v.y; hrow[j+2] = v.z; hrow[j+3] = v.w;
    }
    float mid[D];
    for (int j1 = 0; j1 < D; j1 += 4) {
        float a0 = wb1[j1], a1 = wb1[j1+1], a2 = wb1[j1+2], a3 = wb1[j1+3];
        #pragma unroll
        for (int k = 0; k < D; ++k) {
            float t = hrow[k];
            a0 += t * ww1[k*D + j1];   a1 += t * ww1[k*D + j1+1];
            a2 += t * ww1[k*D + j1+2]; a3 += t * ww1[k*D + j1+3];
        }
        mid[j1]=gelu_exact(a0); mid[j1+1]=gelu_exact(a1);
        mid[j1+2]=gelu_exact(a2); mid[j1+3]=gelu_exact(a3);
    }
    #pragma unroll
    for (int j = 0; j < D; j += 4) {
        float4 v = *(const float4*)(aggr + (size_t)n * D + j);
        hrow[j]=wb2[j]+v.x; hrow[j+1]=wb2[j+1]+v.y;
        hrow[j+2]=wb2[j+2]+v.z; hrow[j+3]=wb2[j+3]+v.w;
    }
    for (int j1 = 0; j1 < D; j1 += 4) {
        float t0=mid[j1], t1=mid[j1+1], t2=mid[j1+2], t3=mid[j1+3];
        #pragma unroll
        for (int j = 0; j < D; ++j)
            hrow[j] += t0*ww2[j1*D+j] + t1*ww2[(j1+1)*D+j]
                     + t2*ww2[(j1+2)*D+j] + t3*ww2[(j1+3)*D+j];
    }
    #pragma unroll
    for (int j = 0; j < D; ++j) hrow[j] = gelu_exact(hrow[j]);
    float o = db2[0];
    for (int j1 = 0; j1 < D; j1 += 4) {
        float a0 = db1[j1], a1 = db1[j1+1], a2 = db1[j1+2], a3 = db1[j1+3];
        #pragma unroll
        for (int k = 0; k < D; ++k) {
            float t = hrow[k];
            a0 += t*dw1[k*D+j1];   a1 += t*dw1[k*D+j1+1];
            a2 += t*dw1[k*D+j1+2]; a3 += t*dw1[k*D+j1+3];
        }
        o += gelu_exact(a0)*dw2[j1] + gelu_exact(a1)*dw2[j1+1]
           + gelu_exact(a2)*dw2[j1+2] + gelu_exact(a3)*dw2[j1+3];
    }
    out[n] = o;
}

extern "C" void kernel_launch(void* const* d_in, const int* in_sizes, int n_in,
                              void* d_out, int out_size, void* d_ws, size_t ws_size,
                              hipStream_t stream) {
    const float* x    = (const float*)d_in[0];
    const float* grid = (const float*)d_in[1];
    const int*   ei   = (const int*)d_in[2];
    const float* p_w1 = (const float*)d_in[4];
    const float* p_b1 = (const float*)d_in[5];
    const float* p_w2 = (const float*)d_in[6];
    const float* p_b2 = (const float*)d_in[7];
    const float* w_w1 = (const float*)d_in[8];
    const float* w_b1 = (const float*)d_in[9];
    const float* w_w2 = (const float*)d_in[10];
    const float* w_b2 = (const float*)d_in[11];
    const float* d_w1 = (const float*)d_in[12];
    const float* d_b1 = (const float*)d_in[13];
    const float* d_w2 = (const float*)d_in[14];
    const float* d_b2 = (const float*)d_in[15];
    float* out = (float*)d_out;

    float* h    = (float*)d_ws;                            // [NN, D] f32
    float* aggr = h + (size_t)NN * D;                      // [NN, D] f32
    int* deg    = (int*)(aggr + (size_t)NN * D);           // [NBKT]
    int* offs   = deg + NBKT;                              // [NBKT+1]
    int* cursor = offs + NBKT + 1;                         // [NBKT]
    int* packed = cursor + NBKT;                           // [NE]
    unsigned short* fragw =
        (unsigned short*)((((uintptr_t)(packed + NE)) + 15) & ~(uintptr_t)15); // [NFRAG*512] u16

    size_t need = ((char*)(fragw + NFRAG * 512)) - (char*)d_ws;

    if (ws_size >= need) {
        pack_frags_kernel<<<(NFRAG * 64 + 255) / 256, 256, 0, stream>>>(
            w_w1, w_w2, d_w1, p_w1, p_w2, fragw);
        hipMemsetAsync(deg, 0, NBKT * sizeof(int), stream);
        project_mfma<<<(NN + 63) / 64, 256, 0, stream>>>(
            x, grid, fragw, p_b1, p_b2, h);
        count_kernel      <<<NCHK, 256, 0, stream>>>(ei, deg);
        scan_bsum_kernel  <<<1,   1024, 0, stream>>>(deg, offs, cursor);
        bin_reserve_kernel<<<NCHK, 256, 0, stream>>>(ei, cursor, packed);
        sortagg_kernel    <<<NBKT, 256, 0, stream>>>(offs, packed, h, aggr);
        update_decode_mfma<<<(NN + 63) / 64, 256, 0, stream>>>(
            h, aggr, fragw, w_b1, w_b2, d_b1, d_w2, d_b2, out);
    } else {
        project_kernel<<<(NN + 255) / 256, 256, 0, stream>>>(
            x, grid, p_w1, p_b1, p_w2, p_b2, h);
        hipMemsetAsync(aggr, 0, (size_t)NN * D * sizeof(float), stream);
        aggregate_kernel<<<(size_t)NE * 64 / 256, 256, 0, stream>>>(ei, h, aggr);
        update_decode_valu<<<(NN + 255) / 256, 256, 0, stream>>>(
            h, aggr, w_w1, w_b1, w_w2, w_b2, d_w1, d_b1, d_w2, d_b2, out);
    }
}

// Round 13
// 158.320 us; speedup vs baseline: 1.1655x; 1.0772x over previous
//
#include <hip/hip_runtime.h>
#include <math.h>

#define NN 100000
#define NE 1600000
#define D 64
#define INDIM 18
#define CHUNKS 256            // edge chunks for count/bin
#define BN 64                 // nodes per bucket (sort)
#define NBKT 1563             // ceil(NN / BN)
#define CAP 1536              // LDS edge capacity per bucket
#define NFRAG 72              // 48 update frags + 8 p_w1 + 16 p_w2

typedef __attribute__((ext_vector_type(8))) short s8b;    // 8 bf16 (4 VGPR)
typedef __attribute__((ext_vector_type(4))) float f32x4;  // MFMA acc

__device__ __forceinline__ float gelu_exact(float x) {
    return 0.5f * x * (1.0f + erff(x * 0.70710678118654752f));
}

// split f32 into bf16 hi + bf16 lo (round-to-nearest-even)
__device__ __forceinline__ void split_bf16(float f, unsigned short& h, unsigned short& l) {
    unsigned int u = __float_as_uint(f);
    unsigned int hb = (u + 0x7FFFu + ((u >> 16) & 1u)) >> 16;
    float hf = __uint_as_float(hb << 16);
    float lo = f - hf;
    unsigned int u2 = __float_as_uint(lo);
    unsigned int lb = (u2 + 0x7FFFu + ((u2 >> 16) & 1u)) >> 16;
    h = (unsigned short)hb; l = (unsigned short)lb;
}

// ---- pack B-fragments (hi/lo bf16, lane-major) ------------------------
__global__ __launch_bounds__(256) void pack_frags_kernel(
    const float* __restrict__ ww1, const float* __restrict__ ww2,
    const float* __restrict__ dw1, const float* __restrict__ pw1,
    const float* __restrict__ pw2, unsigned short* __restrict__ fragw)
{
    int tid = blockIdx.x * 256 + threadIdx.x;
    if (tid >= NFRAG * 64) return;
    int f = tid >> 6, l = tid & 63;
    unsigned short o[8];
    if (f < 48) {
        int x = f & 1, t = (f >> 1) & 3, s = (f >> 3) & 1, layer = f >> 4;
        const float* W = (layer == 0) ? ww1 : ((layer == 1) ? ww2 : dw1);
        #pragma unroll
        for (int j = 0; j < 8; ++j) {
            int k = s * 32 + (l >> 4) * 8 + j;
            int n = t * 16 + (l & 15);
            unsigned short hh, ll;
            split_bf16(W[k * D + n], hh, ll);
            o[j] = x ? ll : hh;
        }
    } else if (f < 56) {
        int g = f - 48, x = g & 1, t = (g >> 1) & 3;
        #pragma unroll
        for (int j = 0; j < 8; ++j) {
            int k = (l >> 4) * 8 + j;
            int n = t * 16 + (l & 15);
            float v = (k < INDIM) ? pw1[k * D + n] : 0.f;
            unsigned short hh, ll;
            split_bf16(v, hh, ll);
            o[j] = x ? ll : hh;
        }
    } else {
        int g = f - 56, x = g & 1, t = (g >> 1) & 3, s = (g >> 3) & 1;
        #pragma unroll
        for (int j = 0; j < 8; ++j) {
            int k = s * 32 + (l >> 4) * 8 + j;
            int n = t * 16 + (l & 15);
            unsigned short hh, ll;
            split_bf16(pw2[k * D + n], hh, ll);
            o[j] = x ? ll : hh;
        }
    }
    uint4 v;
    v.x = (unsigned)o[0] | ((unsigned)o[1] << 16);
    v.y = (unsigned)o[2] | ((unsigned)o[3] << 16);
    v.z = (unsigned)o[4] | ((unsigned)o[5] << 16);
    v.w = (unsigned)o[6] | ((unsigned)o[7] << 16);
    *(uint4*)&fragw[(size_t)f * 512 + l * 8] = v;
}

// -------- project via MFMA: h = (concat(x,grid) @ w1 ..gelu..) @ w2 + b2
__global__ __launch_bounds__(256) void project_mfma(
    const float* __restrict__ x, const float* __restrict__ grid,
    const unsigned short* __restrict__ fragw,
    const float* __restrict__ pb1, const float* __restrict__ pb2,
    float* __restrict__ h)
{
    __shared__ unsigned short midH[64 * 64];
    __shared__ unsigned short midL[64 * 64];
    const int tid = threadIdx.x;
    const int w = tid >> 6, l = tid & 63;
    const int q = l >> 4, c = l & 15;
    const int g0 = blockIdx.x * 64;
    const int rowbase = w * 16;

    union BU { uint4 u; s8b s; };

    const int arow = g0 + rowbase + c;
    const bool ok = arow < NN;
    float fv[8] = {0.f,0.f,0.f,0.f,0.f,0.f,0.f,0.f};
    if (q < 2) {
        if (ok) {
            const float* xp = x + (size_t)arow * 16 + q * 8;
            float4 f0 = *(const float4*)xp;
            float4 f1 = *(const float4*)(xp + 4);
            fv[0]=f0.x; fv[1]=f0.y; fv[2]=f0.z; fv[3]=f0.w;
            fv[4]=f1.x; fv[5]=f1.y; fv[6]=f1.z; fv[7]=f1.w;
        }
    } else if (q == 2) {
        if (ok) {
            float2 g2 = *(const float2*)(grid + (size_t)arow * 2);
            fv[0] = g2.x; fv[1] = g2.y;
        }
    }
    s8b aH[2], aL[2];
    #pragma unroll
    for (int j = 0; j < 8; ++j) {
        unsigned short hh, ll;
        split_bf16(fv[j], hh, ll);
        aH[0][j] = (short)hh; aL[0][j] = (short)ll;
    }

    f32x4 acc[4];
    #pragma unroll
    for (int t = 0; t < 4; ++t) acc[t] = (f32x4){0.f, 0.f, 0.f, 0.f};
    #pragma unroll
    for (int t = 0; t < 4; ++t) {
        BU bh, bl;
        int fb = 48 + t * 2;
        bh.u = *(const uint4*)&fragw[(size_t)fb * 512 + l * 8];
        bl.u = *(const uint4*)&fragw[(size_t)(fb + 1) * 512 + l * 8];
        acc[t] = __builtin_amdgcn_mfma_f32_16x16x32_bf16(aH[0], bh.s, acc[t], 0, 0, 0);
        acc[t] = __builtin_amdgcn_mfma_f32_16x16x32_bf16(aH[0], bl.s, acc[t], 0, 0, 0);
        acc[t] = __builtin_amdgcn_mfma_f32_16x16x32_bf16(aL[0], bh.s, acc[t], 0, 0, 0);
    }

    #pragma unroll
    for (int t = 0; t < 4; ++t) {
        float bias = pb1[t * 16 + c];
        #pragma unroll
        for (int r = 0; r < 4; ++r) {
            int grow = rowbase + q * 4 + r;
            float v = gelu_exact(acc[t][r] + bias);
            unsigned short hh, ll;
            split_bf16(v, hh, ll);
            int byte = ((grow * 128 + (t * 16 + c) * 2)) ^ ((grow & 7) << 4);
            midH[byte >> 1] = hh; midL[byte >> 1] = ll;
        }
    }
    __syncthreads();

    #pragma unroll
    for (int s = 0; s < 2; ++s) {
        int ar = rowbase + c;
        int abyte = (ar * 128 + s * 64 + q * 16) ^ ((ar & 7) << 4);
        aH[s] = *(const s8b*)((const char*)midH + abyte);
        aL[s] = *(const s8b*)((const char*)midL + abyte);
    }
    #pragma unroll
    for (int t = 0; t < 4; ++t) acc[t] = (f32x4){0.f, 0.f, 0.f, 0.f};
    #pragma unroll
    for (int s = 0; s < 2; ++s) {
        #pragma unroll
        for (int t = 0; t < 4; ++t) {
            BU bh, bl;
            int fb = 56 + s * 8 + t * 2;
            bh.u = *(const uint4*)&fragw[(size_t)fb * 512 + l * 8];
            bl.u = *(const uint4*)&fragw[(size_t)(fb + 1) * 512 + l * 8];
            acc[t] = __builtin_amdgcn_mfma_f32_16x16x32_bf16(aH[s], bh.s, acc[t], 0, 0, 0);
            acc[t] = __builtin_amdgcn_mfma_f32_16x16x32_bf16(aH[s], bl.s, acc[t], 0, 0, 0);
            acc[t] = __builtin_amdgcn_mfma_f32_16x16x32_bf16(aL[s], bh.s, acc[t], 0, 0, 0);
        }
    }
    #pragma unroll
    for (int t = 0; t < 4; ++t) {
        float bias = pb2[t * 16 + c];
        #pragma unroll
        for (int r = 0; r < 4; ++r) {
            int row = g0 + rowbase + q * 4 + r;
            if (row < NN) h[(size_t)row * D + t * 16 + c] = acc[t][r] + bias;
        }
    }
}

// ---------------- project VALU (ws fallback) ---------------------------
__global__ __launch_bounds__(256) void project_kernel(
    const float* __restrict__ x, const float* __restrict__ grid,
    const float* __restrict__ w1, const float* __restrict__ b1,
    const float* __restrict__ w2, const float* __restrict__ b2,
    float* __restrict__ h)
{
    int n = blockIdx.x * 256 + threadIdx.x;
    if (n >= NN) return;

    float in[INDIM];
    {
        const float4* xr = (const float4*)(x + (size_t)n * 16);
        float4 a = xr[0], b = xr[1], c = xr[2], d = xr[3];
        in[0]=a.x; in[1]=a.y; in[2]=a.z; in[3]=a.w;
        in[4]=b.x; in[5]=b.y; in[6]=b.z; in[7]=b.w;
        in[8]=c.x; in[9]=c.y; in[10]=c.z; in[11]=c.w;
        in[12]=d.x; in[13]=d.y; in[14]=d.z; in[15]=d.w;
        float2 g = *(const float2*)(grid + (size_t)n * 2);
        in[16]=g.x; in[17]=g.y;
    }

    float mid[D];
    for (int j1 = 0; j1 < D; j1 += 4) {
        float a0 = b1[j1], a1 = b1[j1+1], a2 = b1[j1+2], a3 = b1[j1+3];
        #pragma unroll
        for (int k = 0; k < INDIM; ++k) {
            float t = in[k];
            a0 += t * w1[k*D + j1];
            a1 += t * w1[k*D + j1+1];
            a2 += t * w1[k*D + j1+2];
            a3 += t * w1[k*D + j1+3];
        }
        mid[j1]   = gelu_exact(a0);
        mid[j1+1] = gelu_exact(a1);
        mid[j1+2] = gelu_exact(a2);
        mid[j1+3] = gelu_exact(a3);
    }

    float acc[D];
    #pragma unroll
    for (int j = 0; j < D; ++j) acc[j] = b2[j];
    for (int j1 = 0; j1 < D; j1 += 4) {
        float t0 = mid[j1], t1 = mid[j1+1], t2 = mid[j1+2], t3 = mid[j1+3];
        #pragma unroll
        for (int j = 0; j < D; ++j)
            acc[j] += t0 * w2[j1*D + j]     + t1 * w2[(j1+1)*D + j]
                    + t2 * w2[(j1+2)*D + j] + t3 * w2[(j1+3)*D + j];
    }

    float* hrow = h + (size_t)n * D;
    #pragma unroll
    for (int j = 0; j < D; j += 4) {
        float4 v = { acc[j], acc[j+1], acc[j+2], acc[j+3] };
        *(float4*)(hrow + j) = v;
    }
}

// ---- sort step 1: per-chunk LDS histogram -> counts[chunk][bucket] ----
__global__ __launch_bounds__(256) void count_kernel(
    const int* __restrict__ ei, unsigned short* __restrict__ counts)
{
    __shared__ int s_hist[NBKT];
    const int blk = blockIdx.x, tid = threadIdx.x;
    const int* __restrict__ dst = ei + NE;
    for (int i = tid; i < NBKT; i += 256) s_hist[i] = 0;
    __syncthreads();
    for (int e = blk * 256 + tid; e < NE; e += CHUNKS * 256)
        atomicAdd(&s_hist[dst[e] / BN], 1);
    __syncthreads();
    for (int b = tid; b < NBKT; b += 256)
        counts[(size_t)blk * NBKT + b] = (unsigned short)s_hist[b];
}

// ---- sort step 2: per-bucket column scan over chunks (in place) ------
__global__ __launch_bounds__(256) void scan_cols_kernel(
    unsigned short* __restrict__ counts, int* __restrict__ btotal)
{
    __shared__ int s[256];
    const int g = blockIdx.x, tid = threadIdx.x;
    int v = counts[(size_t)tid * NBKT + g];
    s[tid] = v; __syncthreads();
    for (int off = 1; off < 256; off <<= 1) {
        int val = s[tid];
        int add = (tid >= off) ? s[tid - off] : 0;
        __syncthreads();
        s[tid] = val + add;
        __syncthreads();
    }
    counts[(size_t)tid * NBKT + g] = (unsigned short)(s[tid] - v);   // exclusive
    if (tid == 255) btotal[g] = s[255];
}

// ---- sort step 3: scan bucket totals -> offs[0..NBKT] ----------------
__global__ __launch_bounds__(1024) void scan_bsum_kernel(
    const int* __restrict__ btotal, int* __restrict__ offs)
{
    __shared__ int s[1024];
    const int tid = threadIdx.x;
    int b0 = 2 * tid, b1 = 2 * tid + 1;
    int v0 = (b0 < NBKT) ? btotal[b0] : 0;
    int v1 = (b1 < NBKT) ? btotal[b1] : 0;
    int sum = v0 + v1;
    s[tid] = sum; __syncthreads();
    for (int off = 1; off < 1024; off <<= 1) {
        int val = s[tid];
        int add = (tid >= off) ? s[tid - off] : 0;
        __syncthreads();
        s[tid] = val + add;
        __syncthreads();
    }
    int base = s[tid] - sum;
    if (b0 < NBKT) offs[b0] = base;
    if (b1 < NBKT) offs[b1] = base + v0;
    if (tid == 0)  offs[NBKT] = NE;
}

// ---- sort step 4: scatter packed (src<<6 | dst%64), LDS cursors ------
__global__ __launch_bounds__(256) void bin_kernel(
    const int* __restrict__ ei, const unsigned short* __restrict__ counts,
    const int* __restrict__ offs, int* __restrict__ packed)
{
    __shared__ int s_cur[NBKT];
    const int blk = blockIdx.x, tid = threadIdx.x;
    const int* __restrict__ dst = ei + NE;
    for (int b = tid; b < NBKT; b += 256)
        s_cur[b] = offs[b] + (int)counts[(size_t)blk * NBKT + b];
    __syncthreads();
    for (int e = blk * 256 + tid; e < NE; e += CHUNKS * 256) {
        int d = dst[e];
        int s = ei[e];
        int pos = atomicAdd(&s_cur[d / BN], 1);
        packed[pos] = (s << 6) | (d & (BN - 1));
    }
}

// ---- fused per-bucket node-sort (LDS) + group-wide float4 gather -----
// 16-lane group loads one edge-row float4 per instruction: a wave has
// 32 edges (8 KB) in flight -> 4x the latency-hiding of the 4B/lane form.
__global__ __launch_bounds__(256) void sortagg_kernel(
    const int* __restrict__ offs, const int* __restrict__ packed,
    const float* __restrict__ h, float* __restrict__ aggr)
{
    __shared__ int s_off[BN + 1];
    __shared__ int s_cur[BN];
    __shared__ int s_src[CAP];
    const int b = blockIdx.x, tid = threadIdx.x;
    const int start = offs[b], end = offs[b + 1];
    const int cnt = end - start;
    const int wid = tid >> 6, lane = tid & 63;
    const int base = b * BN;

    if (cnt <= CAP) {
        if (tid < BN) s_cur[tid] = 0;
        __syncthreads();
        for (int e = start + tid; e < end; e += 256)
            atomicAdd(&s_cur[packed[e] & (BN - 1)], 1);
        __syncthreads();
        if (tid < 64) {
            int v = s_cur[tid];
            int incl = v;
            #pragma unroll
            for (int off = 1; off < 64; off <<= 1) {
                int u = __shfl_up(incl, off, 64);
                if (tid >= off) incl += u;
            }
            s_off[tid] = incl - v;
            if (tid == 63) s_off[64] = cnt;
        }
        __syncthreads();
        if (tid < BN) s_cur[tid] = s_off[tid];
        __syncthreads();
        for (int e = start + tid; e < end; e += 256) {
            int p = packed[e];
            int pos = atomicAdd(&s_cur[p & (BN - 1)], 1);
            s_src[pos] = p >> 6;
        }
        __syncthreads();

        const int g = lane >> 4, sl = lane & 15;
        for (int m = wid; m < BN; m += 4) {
            int node = base + m;
            int s0 = s_off[m], s1 = s_off[m + 1];
            float4 a4 = make_float4(0.f, 0.f, 0.f, 0.f);
            for (int e0 = s0; e0 < s1; e0 += 32) {
                float4 v[8];
                #pragma unroll
                for (int k = 0; k < 8; ++k) {
                    int e = e0 + 4 * k + g;
                    v[k] = (e < s1)
                        ? *(const float4*)(h + (size_t)s_src[e] * D + sl * 4)
                        : make_float4(0.f, 0.f, 0.f, 0.f);
                }
                #pragma unroll
                for (int k = 0; k < 8; ++k) {
                    a4.x += v[k].x; a4.y += v[k].y;
                    a4.z += v[k].z; a4.w += v[k].w;
                }
            }
            // fold the 4 lane-groups (lanes l, l+16, l+32, l+48)
            #pragma unroll
            for (int off = 16; off <= 32; off <<= 1) {
                a4.x += __shfl_xor(a4.x, off, 64);
                a4.y += __shfl_xor(a4.y, off, 64);
                a4.z += __shfl_xor(a4.z, off, 64);
                a4.w += __shfl_xor(a4.w, off, 64);
            }
            if (g == 0 && node < NN)
                *(float4*)(aggr + (size_t)node * D + sl * 4) = a4;
        }
    } else {
        for (int m = wid; m < BN; m += 4) {
            int node = base + m;
            if (node < NN) {
                float a = 0.f;
                for (int e = start; e < end; ++e) {
                    int p = packed[e];
                    if ((p & (BN - 1)) == m) a += h[(size_t)(p >> 6) * D + lane];
                }
                aggr[(size_t)node * D + lane] = a;
            }
        }
    }
}

// ---------------- legacy atomic aggregate (ws fallback) ----------------
__global__ __launch_bounds__(256) void aggregate_kernel(
    const int* __restrict__ ei, const float* __restrict__ h,
    float* __restrict__ aggr)
{
    int t = blockIdx.x * 256 + threadIdx.x;
    int e = t >> 6;
    int lane = t & 63;
    if (e >= NE) return;
    int src = ei[e];
    int dst = ei[NE + e];
    float v = h[(size_t)src * D + lane];
    atomicAdd(&aggr[(size_t)dst * D + lane], v);
}

// -------- update+decode via MFMA bf16 hi/lo (3 mfma per GEMM tile) -----
__global__ __launch_bounds__(256) void update_decode_mfma(
    const float* __restrict__ h, const float* __restrict__ aggr,
    const unsigned short* __restrict__ fragw,
    const float* __restrict__ wb1, const float* __restrict__ wb2,
    const float* __restrict__ db1, const float* __restrict__ dw2,
    const float* __restrict__ db2, float* __restrict__ out)
{
    __shared__ unsigned short midH[64 * 64];
    __shared__ unsigned short midL[64 * 64];
    const int tid = threadIdx.x;
    const int w = tid >> 6, l = tid & 63;
    const int q = l >> 4, c = l & 15;
    const int g0 = blockIdx.x * 64;
    const int rowbase = w * 16;

    union BU { uint4 u; s8b s; };

    s8b aH[2], aL[2];
    #pragma unroll
    for (int s = 0; s < 2; ++s) {
        const float* hp = h + (size_t)(g0 + rowbase + c) * D + s * 32 + q * 8;
        float4 f0 = *(const float4*)hp;
        float4 f1 = *(const float4*)(hp + 4);
        float fv[8] = {f0.x, f0.y, f0.z, f0.w, f1.x, f1.y, f1.z, f1.w};
        #pragma unroll
        for (int j = 0; j < 8; ++j) {
            unsigned short hh, ll;
            split_bf16(fv[j], hh, ll);
            aH[s][j] = (short)hh; aL[s][j] = (short)ll;
        }
    }

    f32x4 acc[4];
    #pragma unroll
    for (int t = 0; t < 4; ++t) acc[t] = (f32x4){0.f, 0.f, 0.f, 0.f};

    #pragma unroll
    for (int s = 0; s < 2; ++s) {
        #pragma unroll
        for (int t = 0; t < 4; ++t) {
            BU bh, bl;
            int fb = ((0 * 2 + s) * 4 + t) * 2;
            bh.u = *(const uint4*)&fragw[(size_t)fb * 512 + l * 8];
            bl.u = *(const uint4*)&fragw[(size_t)(fb + 1) * 512 + l * 8];
            acc[t] = __builtin_amdgcn_mfma_f32_16x16x32_bf16(aH[s], bh.s, acc[t], 0, 0, 0);
            acc[t] = __builtin_amdgcn_mfma_f32_16x16x32_bf16(aH[s], bl.s, acc[t], 0, 0, 0);
            acc[t] = __builtin_amdgcn_mfma_f32_16x16x32_bf16(aL[s], bh.s, acc[t], 0, 0, 0);
        }
    }

    #pragma unroll
    for (int t = 0; t < 4; ++t) {
        float bias = wb1[t * 16 + c];
        #pragma unroll
        for (int r = 0; r < 4; ++r) {
            int grow = rowbase + q * 4 + r;
            float v = gelu_exact(acc[t][r] + bias);
            unsigned short hh, ll;
            split_bf16(v, hh, ll);
            int byte = ((grow * 128 + (t * 16 + c) * 2)) ^ ((grow & 7) << 4);
            midH[byte >> 1] = hh; midL[byte >> 1] = ll;
        }
    }
    __syncthreads();

    #pragma unroll
    for (int s = 0; s < 2; ++s) {
        int ar = rowbase + c;
        int abyte = (ar * 128 + s * 64 + q * 16) ^ ((ar & 7) << 4);
        aH[s] = *(const s8b*)((const char*)midH + abyte);
        aL[s] = *(const s8b*)((const char*)midL + abyte);
    }
    #pragma unroll
    for (int t = 0; t < 4; ++t) acc[t] = (f32x4){0.f, 0.f, 0.f, 0.f};
    #pragma unroll
    for (int s = 0; s < 2; ++s) {
        #pragma unroll
        for (int t = 0; t < 4; ++t) {
            BU bh, bl;
            int fb = ((1 * 2 + s) * 4 + t) * 2;
            bh.u = *(const uint4*)&fragw[(size_t)fb * 512 + l * 8];
            bl.u = *(const uint4*)&fragw[(size_t)(fb + 1) * 512 + l * 8];
            acc[t] = __builtin_amdgcn_mfma_f32_16x16x32_bf16(aH[s], bh.s, acc[t], 0, 0, 0);
            acc[t] = __builtin_amdgcn_mfma_f32_16x16x32_bf16(aH[s], bl.s, acc[t], 0, 0, 0);
            acc[t] = __builtin_amdgcn_mfma_f32_16x16x32_bf16(aL[s], bh.s, acc[t], 0, 0, 0);
        }
    }
    __syncthreads();

    #pragma unroll
    for (int t = 0; t < 4; ++t) {
        float bias = wb2[t * 16 + c];
        #pragma unroll
        for (int r = 0; r < 4; ++r) {
            int grow = rowbase + q * 4 + r;
            float ag = aggr[(size_t)(g0 + grow) * D + t * 16 + c];
            float v = gelu_exact(acc[t][r] + bias + ag);
            unsigned short hh, ll;
            split_bf16(v, hh, ll);
            int byte = ((grow * 128 + (t * 16 + c) * 2)) ^ ((grow & 7) << 4);
            midH[byte >> 1] = hh; midL[byte >> 1] = ll;
        }
    }
    __syncthreads();

    #pragma unroll
    for (int s = 0; s < 2; ++s) {
        int ar = rowbase + c;
        int abyte = (ar * 128 + s * 64 + q * 16) ^ ((ar & 7) << 4);
        aH[s] = *(const s8b*)((const char*)midH + abyte);
        aL[s] = *(const s8b*)((const char*)midL + abyte);
    }
    #pragma unroll
    for (int t = 0; t < 4; ++t) acc[t] = (f32x4){0.f, 0.f, 0.f, 0.f};
    #pragma unroll
    for (int s = 0; s < 2; ++s) {
        #pragma unroll
        for (int t = 0; t < 4; ++t) {
            BU bh, bl;
            int fb = ((2 * 2 + s) * 4 + t) * 2;
            bh.u = *(const uint4*)&fragw[(size_t)fb * 512 + l * 8];
            bl.u = *(const uint4*)&fragw[(size_t)(fb + 1) * 512 + l * 8];
            acc[t] = __builtin_amdgcn_mfma_f32_16x16x32_bf16(aH[s], bh.s, acc[t], 0, 0, 0);
            acc[t] = __builtin_amdgcn_mfma_f32_16x16x32_bf16(aH[s], bl.s, acc[t], 0, 0, 0);
            acc[t] = __builtin_amdgcn_mfma_f32_16x16x32_bf16(aL[s], bh.s, acc[t], 0, 0, 0);
        }
    }

    float p[4] = {0.f, 0.f, 0.f, 0.f};
    #pragma unroll
    for (int t = 0; t < 4; ++t) {
        float bias = db1[t * 16 + c];
        float wv = dw2[t * 16 + c];
        #pragma unroll
        for (int r = 0; r < 4; ++r)
            p[r] += gelu_exact(acc[t][r] + bias) * wv;
    }
    #pragma unroll
    for (int m = 1; m < 16; m <<= 1) {
        #pragma unroll
        for (int r = 0; r < 4; ++r) p[r] += __shfl_xor(p[r], m, 16);
    }
    if (c == 0) {
        float b2v = db2[0];
        #pragma unroll
        for (int r = 0; r < 4; ++r) {
            int row = g0 + rowbase + q * 4 + r;
            if (row < NN) out[row] = p[r] + b2v;
        }
    }
}

// ------- legacy VALU update (ws fallback) ------------------------------
__global__ __launch_bounds__(256) void update_decode_valu(
    const float* __restrict__ h, const float* __restrict__ aggr,
    const float* __restrict__ ww1, const float* __restrict__ wb1,
    const float* __restrict__ ww2, const float* __restrict__ wb2,
    const float* __restrict__ dw1, const float* __restrict__ db1,
    const float* __restrict__ dw2, const float* __restrict__ db2,
    float* __restrict__ out)
{
    int n = blockIdx.x * 256 + threadIdx.x;
    if (n >= NN) return;
    float hrow[D];
    #pragma unroll
    for (int j = 0; j < D; j += 4) {
        float4 v = *(const float4*)(h + (size_t)n * D + j);
        hrow[j] = v.x; hrow[j+1] = v.y; hrow[j+2] = v.z; hrow[j+3] = v.w;
    }
    float mid[D];
    for (int j1 = 0; j1 < D; j1 += 4) {
        float a0 = wb1[j1], a1 = wb1[j1+1], a2 = wb1[j1+2], a3 = wb1[j1+3];
        #pragma unroll
        for (int k = 0; k < D; ++k) {
            float t = hrow[k];
            a0 += t * ww1[k*D + j1];   a1 += t * ww1[k*D + j1+1];
            a2 += t * ww1[k*D + j1+2]; a3 += t * ww1[k*D + j1+3];
        }
        mid[j1]=gelu_exact(a0); mid[j1+1]=gelu_exact(a1);
        mid[j1+2]=gelu_exact(a2); mid[j1+3]=gelu_exact(a3);
    }
    #pragma unroll
    for (int j = 0; j < D; j += 4) {
        float4 v = *(const float4*)(aggr + (size_t)n * D + j);
        hrow[j]=wb2[j]+v.x; hrow[j+1]=wb2[j+1]+v.y;
        hrow[j+2]=wb2[j+2]+v.z; hrow[j+3]=wb2[j+3]+v.w;
    }
    for (int j1 = 0; j1 < D; j1 += 4) {
        float t0=mid[j1], t1=mid[j1+1], t2=mid[j1+2], t3=mid[j1+3];
        #pragma unroll
        for (int j = 0; j < D; ++j)
            hrow[j] += t0*ww2[j1*D+j] + t1*ww2[(j1+1)*D+j]
                     + t2*ww2[(j1+2)*D+j] + t3*ww2[(j1+3)*D+j];
    }
    #pragma unroll
    for (int j = 0; j < D; ++j) hrow[j] = gelu_exact(hrow[j]);
    float o = db2[0];
    for (int j1 = 0; j1 < D; j1 += 4) {
        float a0 = db1[j1], a1 = db1[j1+1], a2 = db1[j1+2], a3 = db1[j1+3];
        #pragma unroll
        for (int k = 0; k < D; ++k) {
            float t = hrow[k];
            a0 += t*dw1[k*D+j1];   a1 += t*dw1[k*D+j1+1];
            a2 += t*dw1[k*D+j1+2]; a3 += t*dw1[k*D+j1+3];
        }
        o += gelu_exact(a0)*dw2[j1] + gelu_exact(a1)*dw2[j1+1]
           + gelu_exact(a2)*dw2[j1+2] + gelu_exact(a3)*dw2[j1+3];
    }
    out[n] = o;
}

extern "C" void kernel_launch(void* const* d_in, const int* in_sizes, int n_in,
                              void* d_out, int out_size, void* d_ws, size_t ws_size,
                              hipStream_t stream) {
    const float* x    = (const float*)d_in[0];
    const float* grid = (const float*)d_in[1];
    const int*   ei   = (const int*)d_in[2];
    const float* p_w1 = (const float*)d_in[4];
    const float* p_b1 = (const float*)d_in[5];
    const float* p_w2 = (const float*)d_in[6];
    const float* p_b2 = (const float*)d_in[7];
    const float* w_w1 = (const float*)d_in[8];
    const float* w_b1 = (const float*)d_in[9];
    const float* w_w2 = (const float*)d_in[10];
    const float* w_b2 = (const float*)d_in[11];
    const float* d_w1 = (const float*)d_in[12];
    const float* d_b1 = (const float*)d_in[13];
    const float* d_w2 = (const float*)d_in[14];
    const float* d_b2 = (const float*)d_in[15];
    float* out = (float*)d_out;

    float* h    = (float*)d_ws;                            // [NN, D] f32
    float* aggr = h + (size_t)NN * D;                      // [NN, D] f32
    unsigned short* counts = (unsigned short*)(aggr + (size_t)NN * D); // [CHUNKS][NBKT] u16
    int* btotal = (int*)(counts + (size_t)CHUNKS * NBKT);  // [NBKT]
    int* offs   = btotal + NBKT;                           // [NBKT+1]
    int* packed = offs + NBKT + 1;                         // [NE]
    unsigned short* fragw =
        (unsigned short*)((((uintptr_t)(packed + NE)) + 15) & ~(uintptr_t)15); // [NFRAG*512] u16

    size_t need = ((char*)(fragw + NFRAG * 512)) - (char*)d_ws;

    if (ws_size >= need) {
        pack_frags_kernel<<<(NFRAG * 64 + 255) / 256, 256, 0, stream>>>(
            w_w1, w_w2, d_w1, p_w1, p_w2, fragw);
        project_mfma<<<(NN + 63) / 64, 256, 0, stream>>>(
            x, grid, fragw, p_b1, p_b2, h);
        count_kernel    <<<CHUNKS, 256, 0, stream>>>(ei, counts);
        scan_cols_kernel<<<NBKT,   256, 0, stream>>>(counts, btotal);
        scan_bsum_kernel<<<1,     1024, 0, stream>>>(btotal, offs);
        bin_kernel      <<<CHUNKS, 256, 0, stream>>>(ei, counts, offs, packed);
        sortagg_kernel  <<<NBKT,   256, 0, stream>>>(offs, packed, h, aggr);
        update_decode_mfma<<<(NN + 63) / 64, 256, 0, stream>>>(
            h, aggr, fragw, w_b1, w_b2, d_b1, d_w2, d_b2, out);
    } else {
        project_kernel<<<(NN + 255) / 256, 256, 0, stream>>>(
            x, grid, p_w1, p_b1, p_w2, p_b2, h);
        hipMemsetAsync(aggr, 0, (size_t)NN * D * sizeof(float), stream);
        aggregate_kernel<<<(size_t)NE * 64 / 256, 256, 0, stream>>>(ei, h, aggr);
        update_decode_valu<<<(NN + 255) / 256, 256, 0, stream>>>(
            h, aggr, w_w1, w_b1, w_w2, w_b2, d_w1, d_b1, d_w2, d_b2, out);
    }
}

// Round 14
// 155.139 us; speedup vs baseline: 1.1894x; 1.0205x over previous
//
#include <hip/hip_runtime.h>
#include <math.h>

#define NN 100000
#define NE 1600000
#define D 64
#define INDIM 18
#define CHUNKS 256            // edge chunks for count/bin
#define BN 64                 // nodes per bucket (sort)
#define NBKT 1563             // ceil(NN / BN)
#define NTB 1563              // ceil(NN / 64) MLP tiles
#define CAP 1536              // LDS edge capacity per bucket
#define NFRAG 72              // 48 update frags + 8 p_w1 + 16 p_w2
#define C2ROWS 100032         // NTB*64 (padded)

typedef __attribute__((ext_vector_type(8))) short s8b;    // 8 bf16 (4 VGPR)
typedef __attribute__((ext_vector_type(4))) float f32x4;  // MFMA acc

__device__ __forceinline__ float gelu_exact(float x) {
    return 0.5f * x * (1.0f + erff(x * 0.70710678118654752f));
}

__device__ __forceinline__ void split_bf16(float f, unsigned short& h, unsigned short& l) {
    unsigned int u = __float_as_uint(f);
    unsigned int hb = (u + 0x7FFFu + ((u >> 16) & 1u)) >> 16;
    float hf = __uint_as_float(hb << 16);
    float lo = f - hf;
    unsigned int u2 = __float_as_uint(lo);
    unsigned int lb = (u2 + 0x7FFFu + ((u2 >> 16) & 1u)) >> 16;
    h = (unsigned short)hb; l = (unsigned short)lb;
}

// ---- pack B-fragments (hi/lo bf16, lane-major) ------------------------
__global__ __launch_bounds__(256) void pack_frags_kernel(
    const float* __restrict__ ww1, const float* __restrict__ ww2,
    const float* __restrict__ dw1, const float* __restrict__ pw1,
    const float* __restrict__ pw2, unsigned short* __restrict__ fragw)
{
    int tid = blockIdx.x * 256 + threadIdx.x;
    if (tid >= NFRAG * 64) return;
    int f = tid >> 6, l = tid & 63;
    unsigned short o[8];
    if (f < 48) {
        int x = f & 1, t = (f >> 1) & 3, s = (f >> 3) & 1, layer = f >> 4;
        const float* W = (layer == 0) ? ww1 : ((layer == 1) ? ww2 : dw1);
        #pragma unroll
        for (int j = 0; j < 8; ++j) {
            int k = s * 32 + (l >> 4) * 8 + j;
            int n = t * 16 + (l & 15);
            unsigned short hh, ll;
            split_bf16(W[k * D + n], hh, ll);
            o[j] = x ? ll : hh;
        }
    } else if (f < 56) {
        int g = f - 48, x = g & 1, t = (g >> 1) & 3;
        #pragma unroll
        for (int j = 0; j < 8; ++j) {
            int k = (l >> 4) * 8 + j;
            int n = t * 16 + (l & 15);
            float v = (k < INDIM) ? pw1[k * D + n] : 0.f;
            unsigned short hh, ll;
            split_bf16(v, hh, ll);
            o[j] = x ? ll : hh;
        }
    } else {
        int g = f - 56, x = g & 1, t = (g >> 1) & 3, s = (g >> 3) & 1;
        #pragma unroll
        for (int j = 0; j < 8; ++j) {
            int k = s * 32 + (l >> 4) * 8 + j;
            int n = t * 16 + (l & 15);
            unsigned short hh, ll;
            split_bf16(pw2[k * D + n], hh, ll);
            o[j] = x ? ll : hh;
        }
    }
    uint4 v;
    v.x = (unsigned)o[0] | ((unsigned)o[1] << 16);
    v.y = (unsigned)o[2] | ((unsigned)o[3] << 16);
    v.z = (unsigned)o[4] | ((unsigned)o[5] << 16);
    v.w = (unsigned)o[6] | ((unsigned)o[7] << 16);
    *(uint4*)&fragw[(size_t)f * 512 + l * 8] = v;
}

// ---- fusedA: project_mfma (blocks [0,NTB)) ∪ count (blocks [NTB,NTB+CHUNKS))
__global__ __launch_bounds__(256) void fusedA_kernel(
    const float* __restrict__ x, const float* __restrict__ grid,
    const unsigned short* __restrict__ fragw,
    const float* __restrict__ pb1, const float* __restrict__ pb2,
    float* __restrict__ h,
    const int* __restrict__ ei, unsigned short* __restrict__ counts)
{
    __shared__ unsigned char smem[16384];
    const int tid = threadIdx.x;

    if (blockIdx.x >= NTB) {
        // -------- count chunk --------
        int* s_hist = (int*)smem;
        const int blk = blockIdx.x - NTB;
        const int* __restrict__ dst = ei + NE;
        for (int i = tid; i < NBKT; i += 256) s_hist[i] = 0;
        __syncthreads();
        for (int e = blk * 256 + tid; e < NE; e += CHUNKS * 256)
            atomicAdd(&s_hist[dst[e] / BN], 1);
        __syncthreads();
        for (int b = tid; b < NBKT; b += 256)
            counts[(size_t)blk * NBKT + b] = (unsigned short)s_hist[b];
        return;
    }

    // -------- project tile --------
    unsigned short* midH = (unsigned short*)smem;
    unsigned short* midL = midH + 4096;
    const int w = tid >> 6, l = tid & 63;
    const int q = l >> 4, c = l & 15;
    const int g0 = blockIdx.x * 64;
    const int rowbase = w * 16;

    union BU { uint4 u; s8b s; };

    const int arow = g0 + rowbase + c;
    const bool ok = arow < NN;
    float fv[8] = {0.f,0.f,0.f,0.f,0.f,0.f,0.f,0.f};
    if (q < 2) {
        if (ok) {
            const float* xp = x + (size_t)arow * 16 + q * 8;
            float4 f0 = *(const float4*)xp;
            float4 f1 = *(const float4*)(xp + 4);
            fv[0]=f0.x; fv[1]=f0.y; fv[2]=f0.z; fv[3]=f0.w;
            fv[4]=f1.x; fv[5]=f1.y; fv[6]=f1.z; fv[7]=f1.w;
        }
    } else if (q == 2) {
        if (ok) {
            float2 g2 = *(const float2*)(grid + (size_t)arow * 2);
            fv[0] = g2.x; fv[1] = g2.y;
        }
    }
    s8b aH[2], aL[2];
    #pragma unroll
    for (int j = 0; j < 8; ++j) {
        unsigned short hh, ll;
        split_bf16(fv[j], hh, ll);
        aH[0][j] = (short)hh; aL[0][j] = (short)ll;
    }

    f32x4 acc[4];
    #pragma unroll
    for (int t = 0; t < 4; ++t) acc[t] = (f32x4){0.f, 0.f, 0.f, 0.f};
    #pragma unroll
    for (int t = 0; t < 4; ++t) {
        BU bh, bl;
        int fb = 48 + t * 2;
        bh.u = *(const uint4*)&fragw[(size_t)fb * 512 + l * 8];
        bl.u = *(const uint4*)&fragw[(size_t)(fb + 1) * 512 + l * 8];
        acc[t] = __builtin_amdgcn_mfma_f32_16x16x32_bf16(aH[0], bh.s, acc[t], 0, 0, 0);
        acc[t] = __builtin_amdgcn_mfma_f32_16x16x32_bf16(aH[0], bl.s, acc[t], 0, 0, 0);
        acc[t] = __builtin_amdgcn_mfma_f32_16x16x32_bf16(aL[0], bh.s, acc[t], 0, 0, 0);
    }

    #pragma unroll
    for (int t = 0; t < 4; ++t) {
        float bias = pb1[t * 16 + c];
        #pragma unroll
        for (int r = 0; r < 4; ++r) {
            int grow = rowbase + q * 4 + r;
            float v = gelu_exact(acc[t][r] + bias);
            unsigned short hh, ll;
            split_bf16(v, hh, ll);
            int byte = ((grow * 128 + (t * 16 + c) * 2)) ^ ((grow & 7) << 4);
            midH[byte >> 1] = hh; midL[byte >> 1] = ll;
        }
    }
    __syncthreads();

    #pragma unroll
    for (int s = 0; s < 2; ++s) {
        int ar = rowbase + c;
        int abyte = (ar * 128 + s * 64 + q * 16) ^ ((ar & 7) << 4);
        aH[s] = *(const s8b*)((const char*)midH + abyte);
        aL[s] = *(const s8b*)((const char*)midL + abyte);
    }
    #pragma unroll
    for (int t = 0; t < 4; ++t) acc[t] = (f32x4){0.f, 0.f, 0.f, 0.f};
    #pragma unroll
    for (int s = 0; s < 2; ++s) {
        #pragma unroll
        for (int t = 0; t < 4; ++t) {
            BU bh, bl;
            int fb = 56 + s * 8 + t * 2;
            bh.u = *(const uint4*)&fragw[(size_t)fb * 512 + l * 8];
            bl.u = *(const uint4*)&fragw[(size_t)(fb + 1) * 512 + l * 8];
            acc[t] = __builtin_amdgcn_mfma_f32_16x16x32_bf16(aH[s], bh.s, acc[t], 0, 0, 0);
            acc[t] = __builtin_amdgcn_mfma_f32_16x16x32_bf16(aH[s], bl.s, acc[t], 0, 0, 0);
            acc[t] = __builtin_amdgcn_mfma_f32_16x16x32_bf16(aL[s], bh.s, acc[t], 0, 0, 0);
        }
    }
    #pragma unroll
    for (int t = 0; t < 4; ++t) {
        float bias = pb2[t * 16 + c];
        #pragma unroll
        for (int r = 0; r < 4; ++r) {
            int row = g0 + rowbase + q * 4 + r;
            if (row < NN) h[(size_t)row * D + t * 16 + c] = acc[t][r] + bias;
        }
    }
}

// ---- sort step 2: per-bucket column scan over chunks (in place) ------
__global__ __launch_bounds__(256) void scan_cols_kernel(
    unsigned short* __restrict__ counts, int* __restrict__ btotal)
{
    __shared__ int s[256];
    const int g = blockIdx.x, tid = threadIdx.x;
    int v = counts[(size_t)tid * NBKT + g];
    s[tid] = v; __syncthreads();
    for (int off = 1; off < 256; off <<= 1) {
        int val = s[tid];
        int add = (tid >= off) ? s[tid - off] : 0;
        __syncthreads();
        s[tid] = val + add;
        __syncthreads();
    }
    counts[(size_t)tid * NBKT + g] = (unsigned short)(s[tid] - v);   // exclusive
    if (tid == 255) btotal[g] = s[255];
}

// ---- sort step 3: scan bucket totals -> offs[0..NBKT] ----------------
__global__ __launch_bounds__(1024) void scan_bsum_kernel(
    const int* __restrict__ btotal, int* __restrict__ offs)
{
    __shared__ int s[1024];
    const int tid = threadIdx.x;
    int b0 = 2 * tid, b1 = 2 * tid + 1;
    int v0 = (b0 < NBKT) ? btotal[b0] : 0;
    int v1 = (b1 < NBKT) ? btotal[b1] : 0;
    int sum = v0 + v1;
    s[tid] = sum; __syncthreads();
    for (int off = 1; off < 1024; off <<= 1) {
        int val = s[tid];
        int add = (tid >= off) ? s[tid - off] : 0;
        __syncthreads();
        s[tid] = val + add;
        __syncthreads();
    }
    int base = s[tid] - sum;
    if (b0 < NBKT) offs[b0] = base;
    if (b1 < NBKT) offs[b1] = base + v0;
    if (tid == 0)  offs[NBKT] = NE;
}

// ---- fusedD: bin (blocks [0,CHUNKS)) ∪ upd1 C2-precompute (rest) -----
__global__ __launch_bounds__(256) void fusedD_kernel(
    const int* __restrict__ ei, const unsigned short* __restrict__ counts,
    const int* __restrict__ offs, int* __restrict__ packed,
    const float* __restrict__ h, const unsigned short* __restrict__ fragw,
    const float* __restrict__ wb1, const float* __restrict__ wb2,
    float* __restrict__ C2)
{
    __shared__ unsigned char smem[16384];
    const int tid = threadIdx.x;

    if (blockIdx.x < CHUNKS) {
        // -------- bin chunk --------
        int* s_cur = (int*)smem;
        const int blk = blockIdx.x;
        const int* __restrict__ dst = ei + NE;
        for (int b = tid; b < NBKT; b += 256)
            s_cur[b] = offs[b] + (int)counts[(size_t)blk * NBKT + b];
        __syncthreads();
        for (int e = blk * 256 + tid; e < NE; e += CHUNKS * 256) {
            int d = dst[e];
            int s = ei[e];
            int pos = atomicAdd(&s_cur[d / BN], 1);
            packed[pos] = (s << 6) | (d & (BN - 1));
        }
        return;
    }

    // -------- upd1 tile: C2' = gelu(h@ww1+wb1)@ww2 + wb2 --------
    unsigned short* midH = (unsigned short*)smem;
    unsigned short* midL = midH + 4096;
    const int w = tid >> 6, l = tid & 63;
    const int q = l >> 4, c = l & 15;
    const int g0 = (blockIdx.x - CHUNKS) * 64;
    const int rowbase = w * 16;

    union BU { uint4 u; s8b s; };

    s8b aH[2], aL[2];
    #pragma unroll
    for (int s = 0; s < 2; ++s) {
        const float* hp = h + (size_t)(g0 + rowbase + c) * D + s * 32 + q * 8;
        float4 f0 = *(const float4*)hp;
        float4 f1 = *(const float4*)(hp + 4);
        float fv[8] = {f0.x, f0.y, f0.z, f0.w, f1.x, f1.y, f1.z, f1.w};
        #pragma unroll
        for (int j = 0; j < 8; ++j) {
            unsigned short hh, ll;
            split_bf16(fv[j], hh, ll);
            aH[s][j] = (short)hh; aL[s][j] = (short)ll;
        }
    }

    f32x4 acc[4];
    #pragma unroll
    for (int t = 0; t < 4; ++t) acc[t] = (f32x4){0.f, 0.f, 0.f, 0.f};
    #pragma unroll
    for (int s = 0; s < 2; ++s) {
        #pragma unroll
        for (int t = 0; t < 4; ++t) {
            BU bh, bl;
            int fb = ((0 * 2 + s) * 4 + t) * 2;
            bh.u = *(const uint4*)&fragw[(size_t)fb * 512 + l * 8];
            bl.u = *(const uint4*)&fragw[(size_t)(fb + 1) * 512 + l * 8];
            acc[t] = __builtin_amdgcn_mfma_f32_16x16x32_bf16(aH[s], bh.s, acc[t], 0, 0, 0);
            acc[t] = __builtin_amdgcn_mfma_f32_16x16x32_bf16(aH[s], bl.s, acc[t], 0, 0, 0);
            acc[t] = __builtin_amdgcn_mfma_f32_16x16x32_bf16(aL[s], bh.s, acc[t], 0, 0, 0);
        }
    }

    #pragma unroll
    for (int t = 0; t < 4; ++t) {
        float bias = wb1[t * 16 + c];
        #pragma unroll
        for (int r = 0; r < 4; ++r) {
            int grow = rowbase + q * 4 + r;
            float v = gelu_exact(acc[t][r] + bias);
            unsigned short hh, ll;
            split_bf16(v, hh, ll);
            int byte = ((grow * 128 + (t * 16 + c) * 2)) ^ ((grow & 7) << 4);
            midH[byte >> 1] = hh; midL[byte >> 1] = ll;
        }
    }
    __syncthreads();

    #pragma unroll
    for (int s = 0; s < 2; ++s) {
        int ar = rowbase + c;
        int abyte = (ar * 128 + s * 64 + q * 16) ^ ((ar & 7) << 4);
        aH[s] = *(const s8b*)((const char*)midH + abyte);
        aL[s] = *(const s8b*)((const char*)midL + abyte);
    }
    #pragma unroll
    for (int t = 0; t < 4; ++t) acc[t] = (f32x4){0.f, 0.f, 0.f, 0.f};
    #pragma unroll
    for (int s = 0; s < 2; ++s) {
        #pragma unroll
        for (int t = 0; t < 4; ++t) {
            BU bh, bl;
            int fb = ((1 * 2 + s) * 4 + t) * 2;
            bh.u = *(const uint4*)&fragw[(size_t)fb * 512 + l * 8];
            bl.u = *(const uint4*)&fragw[(size_t)(fb + 1) * 512 + l * 8];
            acc[t] = __builtin_amdgcn_mfma_f32_16x16x32_bf16(aH[s], bh.s, acc[t], 0, 0, 0);
            acc[t] = __builtin_amdgcn_mfma_f32_16x16x32_bf16(aH[s], bl.s, acc[t], 0, 0, 0);
            acc[t] = __builtin_amdgcn_mfma_f32_16x16x32_bf16(aL[s], bh.s, acc[t], 0, 0, 0);
        }
    }

    #pragma unroll
    for (int t = 0; t < 4; ++t) {
        float bias = wb2[t * 16 + c];
        #pragma unroll
        for (int r = 0; r < 4; ++r) {
            int grow = rowbase + q * 4 + r;
            C2[(size_t)(g0 + grow) * D + t * 16 + c] = acc[t][r] + bias;
        }
    }
}

// ---- fused per-bucket node-sort (LDS) + group-wide float4 gather -----
__global__ __launch_bounds__(256) void sortagg_kernel(
    const int* __restrict__ offs, const int* __restrict__ packed,
    const float* __restrict__ h, float* __restrict__ aggr)
{
    __shared__ int s_off[BN + 1];
    __shared__ int s_cur[BN];
    __shared__ int s_src[CAP];
    const int b = blockIdx.x, tid = threadIdx.x;
    const int start = offs[b], end = offs[b + 1];
    const int cnt = end - start;
    const int wid = tid >> 6, lane = tid & 63;
    const int base = b * BN;

    if (cnt <= CAP) {
        if (tid < BN) s_cur[tid] = 0;
        __syncthreads();
        for (int e = start + tid; e < end; e += 256)
            atomicAdd(&s_cur[packed[e] & (BN - 1)], 1);
        __syncthreads();
        if (tid < 64) {
            int v = s_cur[tid];
            int incl = v;
            #pragma unroll
            for (int off = 1; off < 64; off <<= 1) {
                int u = __shfl_up(incl, off, 64);
                if (tid >= off) incl += u;
            }
            s_off[tid] = incl - v;
            if (tid == 63) s_off[64] = cnt;
        }
        __syncthreads();
        if (tid < BN) s_cur[tid] = s_off[tid];
        __syncthreads();
        for (int e = start + tid; e < end; e += 256) {
            int p = packed[e];
            int pos = atomicAdd(&s_cur[p & (BN - 1)], 1);
            s_src[pos] = p >> 6;
        }
        __syncthreads();

        const int g = lane >> 4, sl = lane & 15;
        for (int m = wid; m < BN; m += 4) {
            int node = base + m;
            int s0 = s_off[m], s1 = s_off[m + 1];
            float4 a4 = make_float4(0.f, 0.f, 0.f, 0.f);
            for (int e0 = s0; e0 < s1; e0 += 32) {
                float4 v[8];
                #pragma unroll
                for (int k = 0; k < 8; ++k) {
                    int e = e0 + 4 * k + g;
                    v[k] = (e < s1)
                        ? *(const float4*)(h + (size_t)s_src[e] * D + sl * 4)
                        : make_float4(0.f, 0.f, 0.f, 0.f);
                }
                #pragma unroll
                for (int k = 0; k < 8; ++k) {
                    a4.x += v[k].x; a4.y += v[k].y;
                    a4.z += v[k].z; a4.w += v[k].w;
                }
            }
            #pragma unroll
            for (int off = 16; off <= 32; off <<= 1) {
                a4.x += __shfl_xor(a4.x, off, 64);
                a4.y += __shfl_xor(a4.y, off, 64);
                a4.z += __shfl_xor(a4.z, off, 64);
                a4.w += __shfl_xor(a4.w, off, 64);
            }
            if (g == 0 && node < NN)
                *(float4*)(aggr + (size_t)node * D + sl * 4) = a4;
        }
    } else {
        for (int m = wid; m < BN; m += 4) {
            int node = base + m;
            if (node < NN) {
                float a = 0.f;
                for (int e = start; e < end; ++e) {
                    int p = packed[e];
                    if ((p & (BN - 1)) == m) a += h[(size_t)(p >> 6) * D + lane];
                }
                aggr[(size_t)node * D + lane] = a;
            }
        }
    }
}

// ---- updF: u = gelu(C2' + aggr); out = decode(u) ---------------------
__global__ __launch_bounds__(256) void updF_kernel(
    const float* __restrict__ C2, const float* __restrict__ aggr,
    const unsigned short* __restrict__ fragw,
    const float* __restrict__ db1, const float* __restrict__ dw2,
    const float* __restrict__ db2, float* __restrict__ out)
{
    __shared__ unsigned short midH[64 * 64];
    __shared__ unsigned short midL[64 * 64];
    const int tid = threadIdx.x;
    const int w = tid >> 6, l = tid & 63;
    const int q = l >> 4, c = l & 15;
    const int g0 = blockIdx.x * 64;
    const int rowbase = w * 16;

    union BU { uint4 u; s8b s; };

    #pragma unroll
    for (int t = 0; t < 4; ++t) {
        #pragma unroll
        for (int r = 0; r < 4; ++r) {
            int grow = rowbase + q * 4 + r;
            int row = g0 + grow;
            float c2 = C2[(size_t)row * D + t * 16 + c];
            float ag = (row < NN) ? aggr[(size_t)row * D + t * 16 + c] : 0.f;
            float v = gelu_exact(c2 + ag);
            unsigned short hh, ll;
            split_bf16(v, hh, ll);
            int byte = ((grow * 128 + (t * 16 + c) * 2)) ^ ((grow & 7) << 4);
            midH[byte >> 1] = hh; midL[byte >> 1] = ll;
        }
    }
    __syncthreads();

    s8b aH[2], aL[2];
    #pragma unroll
    for (int s = 0; s < 2; ++s) {
        int ar = rowbase + c;
        int abyte = (ar * 128 + s * 64 + q * 16) ^ ((ar & 7) << 4);
        aH[s] = *(const s8b*)((const char*)midH + abyte);
        aL[s] = *(const s8b*)((const char*)midL + abyte);
    }
    f32x4 acc[4];
    #pragma unroll
    for (int t = 0; t < 4; ++t) acc[t] = (f32x4){0.f, 0.f, 0.f, 0.f};
    #pragma unroll
    for (int s = 0; s < 2; ++s) {
        #pragma unroll
        for (int t = 0; t < 4; ++t) {
            BU bh, bl;
            int fb = ((2 * 2 + s) * 4 + t) * 2;
            bh.u = *(const uint4*)&fragw[(size_t)fb * 512 + l * 8];
            bl.u = *(const uint4*)&fragw[(size_t)(fb + 1) * 512 + l * 8];
            acc[t] = __builtin_amdgcn_mfma_f32_16x16x32_bf16(aH[s], bh.s, acc[t], 0, 0, 0);
            acc[t] = __builtin_amdgcn_mfma_f32_16x16x32_bf16(aH[s], bl.s, acc[t], 0, 0, 0);
            acc[t] = __builtin_amdgcn_mfma_f32_16x16x32_bf16(aL[s], bh.s, acc[t], 0, 0, 0);
        }
    }

    float p[4] = {0.f, 0.f, 0.f, 0.f};
    #pragma unroll
    for (int t = 0; t < 4; ++t) {
        float bias = db1[t * 16 + c];
        float wv = dw2[t * 16 + c];
        #pragma unroll
        for (int r = 0; r < 4; ++r)
            p[r] += gelu_exact(acc[t][r] + bias) * wv;
    }
    #pragma unroll
    for (int m = 1; m < 16; m <<= 1) {
        #pragma unroll
        for (int r = 0; r < 4; ++r) p[r] += __shfl_xor(p[r], m, 16);
    }
    if (c == 0) {
        float b2v = db2[0];
        #pragma unroll
        for (int r = 0; r < 4; ++r) {
            int row = g0 + rowbase + q * 4 + r;
            if (row < NN) out[row] = p[r] + b2v;
        }
    }
}

// -------- mid-tier: full update+decode (no C2 buffer) ------------------
__global__ __launch_bounds__(256) void update_decode_mfma(
    const float* __restrict__ h, const float* __restrict__ aggr,
    const unsigned short* __restrict__ fragw,
    const float* __restrict__ wb1, const float* __restrict__ wb2,
    const float* __restrict__ db1, const float* __restrict__ dw2,
    const float* __restrict__ db2, float* __restrict__ out)
{
    __shared__ unsigned short midH[64 * 64];
    __shared__ unsigned short midL[64 * 64];
    const int tid = threadIdx.x;
    const int w = tid >> 6, l = tid & 63;
    const int q = l >> 4, c = l & 15;
    const int g0 = blockIdx.x * 64;
    const int rowbase = w * 16;

    union BU { uint4 u; s8b s; };

    s8b aH[2], aL[2];
    #pragma unroll
    for (int s = 0; s < 2; ++s) {
        const float* hp = h + (size_t)(g0 + rowbase + c) * D + s * 32 + q * 8;
        float4 f0 = *(const float4*)hp;
        float4 f1 = *(const float4*)(hp + 4);
        float fv[8] = {f0.x, f0.y, f0.z, f0.w, f1.x, f1.y, f1.z, f1.w};
        #pragma unroll
        for (int j = 0; j < 8; ++j) {
            unsigned short hh, ll;
            split_bf16(fv[j], hh, ll);
            aH[s][j] = (short)hh; aL[s][j] = (short)ll;
        }
    }

    f32x4 acc[4];
    #pragma unroll
    for (int t = 0; t < 4; ++t) acc[t] = (f32x4){0.f, 0.f, 0.f, 0.f};
    #pragma unroll
    for (int s = 0; s < 2; ++s) {
        #pragma unroll
        for (int t = 0; t < 4; ++t) {
            BU bh, bl;
            int fb = ((0 * 2 + s) * 4 + t) * 2;
            bh.u = *(const uint4*)&fragw[(size_t)fb * 512 + l * 8];
            bl.u = *(const uint4*)&fragw[(size_t)(fb + 1) * 512 + l * 8];
            acc[t] = __builtin_amdgcn_mfma_f32_16x16x32_bf16(aH[s], bh.s, acc[t], 0, 0, 0);
            acc[t] = __builtin_amdgcn_mfma_f32_16x16x32_bf16(aH[s], bl.s, acc[t], 0, 0, 0);
            acc[t] = __builtin_amdgcn_mfma_f32_16x16x32_bf16(aL[s], bh.s, acc[t], 0, 0, 0);
        }
    }

    #pragma unroll
    for (int t = 0; t < 4; ++t) {
        float bias = wb1[t * 16 + c];
        #pragma unroll
        for (int r = 0; r < 4; ++r) {
            int grow = rowbase + q * 4 + r;
            float v = gelu_exact(acc[t][r] + bias);
            unsigned short hh, ll;
            split_bf16(v, hh, ll);
            int byte = ((grow * 128 + (t * 16 + c) * 2)) ^ ((grow & 7) << 4);
            midH[byte >> 1] = hh; midL[byte >> 1] = ll;
        }
    }
    __syncthreads();

    #pragma unroll
    for (int s = 0; s < 2; ++s) {
        int ar = rowbase + c;
        int abyte = (ar * 128 + s * 64 + q * 16) ^ ((ar & 7) << 4);
        aH[s] = *(const s8b*)((const char*)midH + abyte);
        aL[s] = *(const s8b*)((const char*)midL + abyte);
    }
    #pragma unroll
    for (int t = 0; t < 4; ++t) acc[t] = (f32x4){0.f, 0.f, 0.f, 0.f};
    #pragma unroll
    for (int s = 0; s < 2; ++s) {
        #pragma unroll
        for (int t = 0; t < 4; ++t) {
            BU bh, bl;
            int fb = ((1 * 2 + s) * 4 + t) * 2;
            bh.u = *(const uint4*)&fragw[(size_t)fb * 512 + l * 8];
            bl.u = *(const uint4*)&fragw[(size_t)(fb + 1) * 512 + l * 8];
            acc[t] = __builtin_amdgcn_mfma_f32_16x16x32_bf16(aH[s], bh.s, acc[t], 0, 0, 0);
            acc[t] = __builtin_amdgcn_mfma_f32_16x16x32_bf16(aH[s], bl.s, acc[t], 0, 0, 0);
            acc[t] = __builtin_amdgcn_mfma_f32_16x16x32_bf16(aL[s], bh.s, acc[t], 0, 0, 0);
        }
    }
    __syncthreads();

    #pragma unroll
    for (int t = 0; t < 4; ++t) {
        float bias = wb2[t * 16 + c];
        #pragma unroll
        for (int r = 0; r < 4; ++r) {
            int grow = rowbase + q * 4 + r;
            float ag = aggr[(size_t)(g0 + grow) * D + t * 16 + c];
            float v = gelu_exact(acc[t][r] + bias + ag);
            unsigned short hh, ll;
            split_bf16(v, hh, ll);
            int byte = ((grow * 128 + (t * 16 + c) * 2)) ^ ((grow & 7) << 4);
            midH[byte >> 1] = hh; midL[byte >> 1] = ll;
        }
    }
    __syncthreads();

    #pragma unroll
    for (int s = 0; s < 2; ++s) {
        int ar = rowbase + c;
        int abyte = (ar * 128 + s * 64 + q * 16) ^ ((ar & 7) << 4);
        aH[s] = *(const s8b*)((const char*)midH + abyte);
        aL[s] = *(const s8b*)((const char*)midL + abyte);
    }
    #pragma unroll
    for (int t = 0; t < 4; ++t) acc[t] = (f32x4){0.f, 0.f, 0.f, 0.f};
    #pragma unroll
    for (int s = 0; s < 2; ++s) {
        #pragma unroll
        for (int t = 0; t < 4; ++t) {
            BU bh, bl;
            int fb = ((2 * 2 + s) * 4 + t) * 2;
            bh.u = *(const uint4*)&fragw[(size_t)fb * 512 + l * 8];
            bl.u = *(const uint4*)&fragw[(size_t)(fb + 1) * 512 + l * 8];
            acc[t] = __builtin_amdgcn_mfma_f32_16x16x32_bf16(aH[s], bh.s, acc[t], 0, 0, 0);
            acc[t] = __builtin_amdgcn_mfma_f32_16x16x32_bf16(aH[s], bl.s, acc[t], 0, 0, 0);
            acc[t] = __builtin_amdgcn_mfma_f32_16x16x32_bf16(aL[s], bh.s, acc[t], 0, 0, 0);
        }
    }

    float p[4] = {0.f, 0.f, 0.f, 0.f};
    #pragma unroll
    for (int t = 0; t < 4; ++t) {
        float bias = db1[t * 16 + c];
        float wv = dw2[t * 16 + c];
        #pragma unroll
        for (int r = 0; r < 4; ++r)
            p[r] += gelu_exact(acc[t][r] + bias) * wv;
    }
    #pragma unroll
    for (int m = 1; m < 16; m <<= 1) {
        #pragma unroll
        for (int r = 0; r < 4; ++r) p[r] += __shfl_xor(p[r], m, 16);
    }
    if (c == 0) {
        float b2v = db2[0];
        #pragma unroll
        for (int r = 0; r < 4; ++r) {
            int row = g0 + rowbase + q * 4 + r;
            if (row < NN) out[row] = p[r] + b2v;
        }
    }
}

// ---------------- legacy fallbacks (tiny ws) ---------------------------
__global__ __launch_bounds__(256) void project_kernel(
    const float* __restrict__ x, const float* __restrict__ grid,
    const float* __restrict__ w1, const float* __restrict__ b1,
    const float* __restrict__ w2, const float* __restrict__ b2,
    float* __restrict__ h)
{
    int n = blockIdx.x * 256 + threadIdx.x;
    if (n >= NN) return;
    float in[INDIM];
    {
        const float4* xr = (const float4*)(x + (size_t)n * 16);
        float4 a = xr[0], b = xr[1], c = xr[2], d = xr[3];
        in[0]=a.x; in[1]=a.y; in[2]=a.z; in[3]=a.w;
        in[4]=b.x; in[5]=b.y; in[6]=b.z; in[7]=b.w;
        in[8]=c.x; in[9]=c.y; in[10]=c.z; in[11]=c.w;
        in[12]=d.x; in[13]=d.y; in[14]=d.z; in[15]=d.w;
        float2 g = *(const float2*)(grid + (size_t)n * 2);
        in[16]=g.x; in[17]=g.y;
    }
    float mid[D];
    for (int j1 = 0; j1 < D; j1 += 4) {
        float a0 = b1[j1], a1 = b1[j1+1], a2 = b1[j1+2], a3 = b1[j1+3];
        #pragma unroll
        for (int k = 0; k < INDIM; ++k) {
            float t = in[k];
            a0 += t * w1[k*D + j1];   a1 += t * w1[k*D + j1+1];
            a2 += t * w1[k*D + j1+2]; a3 += t * w1[k*D + j1+3];
        }
        mid[j1]=gelu_exact(a0); mid[j1+1]=gelu_exact(a1);
        mid[j1+2]=gelu_exact(a2); mid[j1+3]=gelu_exact(a3);
    }
    float acc[D];
    #pragma unroll
    for (int j = 0; j < D; ++j) acc[j] = b2[j];
    for (int j1 = 0; j1 < D; j1 += 4) {
        float t0 = mid[j1], t1 = mid[j1+1], t2 = mid[j1+2], t3 = mid[j1+3];
        #pragma unroll
        for (int j = 0; j < D; ++j)
            acc[j] += t0 * w2[j1*D + j]     + t1 * w2[(j1+1)*D + j]
                    + t2 * w2[(j1+2)*D + j] + t3 * w2[(j1+3)*D + j];
    }
    float* hrow = h + (size_t)n * D;
    #pragma unroll
    for (int j = 0; j < D; j += 4) {
        float4 v = { acc[j], acc[j+1], acc[j+2], acc[j+3] };
        *(float4*)(hrow + j) = v;
    }
}

__global__ __launch_bounds__(256) void aggregate_kernel(
    const int* __restrict__ ei, const float* __restrict__ h,
    float* __restrict__ aggr)
{
    int t = blockIdx.x * 256 + threadIdx.x;
    int e = t >> 6;
    int lane = t & 63;
    if (e >= NE) return;
    int src = ei[e];
    int dst = ei[NE + e];
    float v = h[(size_t)src * D + lane];
    atomicAdd(&aggr[(size_t)dst * D + lane], v);
}

__global__ __launch_bounds__(256) void update_decode_valu(
    const float* __restrict__ h, const float* __restrict__ aggr,
    const float* __restrict__ ww1, const float* __restrict__ wb1,
    const float* __restrict__ ww2, const float* __restrict__ wb2,
    const float* __restrict__ dw1, const float* __restrict__ db1,
    const float* __restrict__ dw2, const float* __restrict__ db2,
    float* __restrict__ out)
{
    int n = blockIdx.x * 256 + threadIdx.x;
    if (n >= NN) return;
    float hrow[D];
    #pragma unroll
    for (int j = 0; j < D; j += 4) {
        float4 v = *(const float4*)(h + (size_t)n * D + j);
        hrow[j] = v.x; hrow[j+1] = v.y; hrow[j+2] = v.z; hrow[j+3] = v.w;
    }
    float mid[D];
    for (int j1 = 0; j1 < D; j1 += 4) {
        float a0 = wb1[j1], a1 = wb1[j1+1], a2 = wb1[j1+2], a3 = wb1[j1+3];
        #pragma unroll
        for (int k = 0; k < D; ++k) {
            float t = hrow[k];
            a0 += t * ww1[k*D + j1];   a1 += t * ww1[k*D + j1+1];
            a2 += t * ww1[k*D + j1+2]; a3 += t * ww1[k*D + j1+3];
        }
        mid[j1]=gelu_exact(a0); mid[j1+1]=gelu_exact(a1);
        mid[j1+2]=gelu_exact(a2); mid[j1+3]=gelu_exact(a3);
    }
    #pragma unroll
    for (int j = 0; j < D; j += 4) {
        float4 v = *(const float4*)(aggr + (size_t)n * D + j);
        hrow[j]=wb2[j]+v.x; hrow[j+1]=wb2[j+1]+v.y;
        hrow[j+2]=wb2[j+2]+v.z; hrow[j+3]=wb2[j+3]+v.w;
    }
    for (int j1 = 0; j1 < D; j1 += 4) {
        float t0=mid[j1], t1=mid[j1+1], t2=mid[j1+2], t3=mid[j1+3];
        #pragma unroll
        for (int j = 0; j < D; ++j)
            hrow[j] += t0*ww2[j1*D+j] + t1*ww2[(j1+1)*D+j]
                     + t2*ww2[(j1+2)*D+j] + t3*ww2[(j1+3)*D+j];
    }
    #pragma unroll
    for (int j = 0; j < D; ++j) hrow[j] = gelu_exact(hrow[j]);
    float o = db2[0];
    for (int j1 = 0; j1 < D; j1 += 4) {
        float a0 = db1[j1], a1 = db1[j1+1], a2 = db1[j1+2], a3 = db1[j1+3];
        #pragma unroll
        for (int k = 0; k < D; ++k) {
            float t = hrow[k];
            a0 += t*dw1[k*D+j1];   a1 += t*dw1[k*D+j1+1];
            a2 += t*dw1[k*D+j1+2]; a3 += t*dw1[k*D+j1+3];
        }
        o += gelu_exact(a0)*dw2[j1] + gelu_exact(a1)*dw2[j1+1]
           + gelu_exact(a2)*dw2[j1+2] + gelu_exact(a3)*dw2[j1+3];
    }
    out[n] = o;
}

extern "C" void kernel_launch(void* const* d_in, const int* in_sizes, int n_in,
                              void* d_out, int out_size, void* d_ws, size_t ws_size,
                              hipStream_t stream) {
    const float* x    = (const float*)d_in[0];
    const float* grid = (const float*)d_in[1];
    const int*   ei   = (const int*)d_in[2];
    const float* p_w1 = (const float*)d_in[4];
    const float* p_b1 = (const float*)d_in[5];
    const float* p_w2 = (const float*)d_in[6];
    const float* p_b2 = (const float*)d_in[7];
    const float* w_w1 = (const float*)d_in[8];
    const float* w_b1 = (const float*)d_in[9];
    const float* w_w2 = (const float*)d_in[10];
    const float* w_b2 = (const float*)d_in[11];
    const float* d_w1 = (const float*)d_in[12];
    const float* d_b1 = (const float*)d_in[13];
    const float* d_w2 = (const float*)d_in[14];
    const float* d_b2 = (const float*)d_in[15];
    float* out = (float*)d_out;

    float* h    = (float*)d_ws;                            // [NN, D] f32
    float* aggr = h + (size_t)NN * D;                      // [NN, D] f32
    unsigned short* counts = (unsigned short*)(aggr + (size_t)NN * D); // [CHUNKS][NBKT] u16
    int* btotal = (int*)(counts + (size_t)CHUNKS * NBKT);  // [NBKT]
    int* offs   = btotal + NBKT;                           // [NBKT+1]
    int* packed = offs + NBKT + 1;                         // [NE]
    unsigned short* fragw =
        (unsigned short*)((((uintptr_t)(packed + NE)) + 15) & ~(uintptr_t)15); // [NFRAG*512] u16
    float* C2 = (float*)((((uintptr_t)(fragw + NFRAG * 512)) + 15) & ~(uintptr_t)15); // [C2ROWS*D]

    size_t need_base = ((char*)(fragw + NFRAG * 512)) - (char*)d_ws;
    size_t need_full = ((char*)(C2 + (size_t)C2ROWS * D)) - (char*)d_ws;

    if (ws_size >= need_full) {
        pack_frags_kernel<<<(NFRAG * 64 + 255) / 256, 256, 0, stream>>>(
            w_w1, w_w2, d_w1, p_w1, p_w2, fragw);
        fusedA_kernel<<<NTB + CHUNKS, 256, 0, stream>>>(
            x, grid, fragw, p_b1, p_b2, h, ei, counts);
        scan_cols_kernel<<<NBKT, 256, 0, stream>>>(counts, btotal);
        scan_bsum_kernel<<<1,   1024, 0, stream>>>(btotal, offs);
        fusedD_kernel<<<CHUNKS + NTB, 256, 0, stream>>>(
            ei, counts, offs, packed, h, fragw, w_b1, w_b2, C2);
        sortagg_kernel<<<NBKT, 256, 0, stream>>>(offs, packed, h, aggr);
        updF_kernel<<<NTB, 256, 0, stream>>>(
            C2, aggr, fragw, d_b1, d_w2, d_b2, out);
    } else if (ws_size >= need_base) {
        pack_frags_kernel<<<(NFRAG * 64 + 255) / 256, 256, 0, stream>>>(
            w_w1, w_w2, d_w1, p_w1, p_w2, fragw);
        fusedA_kernel<<<NTB + CHUNKS, 256, 0, stream>>>(
            x, grid, fragw, p_b1, p_b2, h, ei, counts);
        scan_cols_kernel<<<NBKT, 256, 0, stream>>>(counts, btotal);
        scan_bsum_kernel<<<1,   1024, 0, stream>>>(btotal, offs);
        fusedD_kernel<<<CHUNKS, 256, 0, stream>>>(          // bin blocks only
            ei, counts, offs, packed, h, fragw, w_b1, w_b2, (float*)0);
        sortagg_kernel<<<NBKT, 256, 0, stream>>>(offs, packed, h, aggr);
        update_decode_mfma<<<NTB, 256, 0, stream>>>(
            h, aggr, fragw, w_b1, w_b2, d_b1, d_w2, d_b2, out);
    } else {
        project_kernel<<<(NN + 255) / 256, 256, 0, stream>>>(
            x, grid, p_w1, p_b1, p_w2, p_b2, h);
        hipMemsetAsync(aggr, 0, (size_t)NN * D * sizeof(float), stream);
        aggregate_kernel<<<(size_t)NE * 64 / 256, 256, 0, stream>>>(ei, h, aggr);
        update_decode_valu<<<(NN + 255) / 256, 256, 0, stream>>>(
            h, aggr, w_w1, w_b1, w_w2, w_b2, d_w1, d_b1, d_w2, d_b2, out);
    }
}